// Round 10
// baseline (383.350 us; speedup 1.0000x reference)
//
#include <hip/hip_runtime.h>
#include <hip/hip_bf16.h>
#include <math.h>

#define B_     8192
#define LATENT 32
#define CIN    128
#define HID    256
#define ACTD   16
#define NE     8
#define GH     128
#define IN0    160   // LATENT + CIN
#define INTER  288   // HID + LATENT

typedef __attribute__((ext_vector_type(8))) short short8;
typedef __attribute__((ext_vector_type(4))) short short4v;
typedef __attribute__((ext_vector_type(4))) float f32x4;
typedef __attribute__((ext_vector_type(4))) int   i32x4;

__device__ __forceinline__ float elu1(float x) { return x > 0.0f ? x : expm1f(x); }

__device__ __forceinline__ unsigned short bfh(float v) {
    __hip_bfloat16 b = __float2bfloat16(v);
    return *reinterpret_cast<unsigned short*>(&b);
}
__device__ __forceinline__ float bf2f(unsigned short u) {
    __hip_bfloat16 b;
    *reinterpret_cast<unsigned short*>(&b) = u;
    return __bfloat162float(b);
}
__device__ __forceinline__ void gload16(const unsigned short* g, const char* lds) {
    __builtin_amdgcn_global_load_lds((const __attribute__((address_space(1))) void*)g,
                                     (__attribute__((address_space(3))) void*)lds, 16, 0, 0);
}
__device__ __forceinline__ short8 as_s8(i32x4 v) {
    union U { i32x4 a; short8 b; } u; u.a = v; return u.b;
}

// ---------- prep (gather form): coalesced short8 writes, strided reads ----------
__global__ __launch_bounds__(256) void k_prep_g(
    const float* __restrict__ w0, const float* __restrict__ w1, const float* __restrict__ w2,
    const float* __restrict__ g0w, const float* __restrict__ g1w,
    unsigned short* __restrict__ T0h, unsigned short* __restrict__ T0l,
    unsigned short* __restrict__ T1h, unsigned short* __restrict__ T1l,
    unsigned short* __restrict__ T2h, unsigned short* __restrict__ T2l,
    unsigned short* __restrict__ G0h, unsigned short* __restrict__ G0l,
    unsigned short* __restrict__ G1h, unsigned short* __restrict__ G1l)
{
    int g = blockIdx.x * 256 + threadIdx.x;
    const float* src; int stride; size_t dst; unsigned short *H, *L;
    if (g < 40960) {                       // T0: [8][160][256] -> [8*256][160]
        int e = g / 5120, r = g % 5120, o = r / 20, i0 = (r % 20) * 8;
        src = w0 + ((size_t)e * 160 + i0) * 256 + o; stride = 256;
        dst = ((size_t)e * 256 + o) * 160 + i0; H = T0h; L = T0l;
    } else if (g < 114688) {               // T1: [8][288][256] -> [8*256][288]
        int t = g - 40960;
        int e = t / 9216, r = t % 9216, o = r / 36, i0 = (r % 36) * 8;
        src = w1 + ((size_t)e * 288 + i0) * 256 + o; stride = 256;
        dst = ((size_t)e * 256 + o) * 288 + i0; H = T1h; L = T1l;
    } else if (g < 119296) {               // T2: [8][288][16] -> [8*16][288]
        int t = g - 114688;
        int e = t / 576, r = t % 576, o = r / 36, i0 = (r % 36) * 8;
        src = w2 + ((size_t)e * 288 + i0) * 16 + o; stride = 16;
        dst = ((size_t)e * 16 + o) * 288 + i0; H = T2h; L = T2l;
    } else if (g < 121856) {               // G0: [160][128] -> [128][160]
        int t = g - 119296;
        int o = t / 20, i0 = (t % 20) * 8;
        src = g0w + (size_t)i0 * 128 + o; stride = 128;
        dst = (size_t)o * 160 + i0; H = G0h; L = G0l;
    } else if (g < 123904) {               // G1: [128][128] -> [128][128]
        int t = g - 121856;
        int o = t / 16, i0 = (t % 16) * 8;
        src = g1w + (size_t)i0 * 128 + o; stride = 128;
        dst = (size_t)o * 128 + i0; H = G1h; L = G1l;
    } else return;
    unsigned short hh[8], ll[8];
    #pragma unroll
    for (int j = 0; j < 8; ++j) {
        float v = src[(size_t)j * stride];
        hh[j] = bfh(v);
        ll[j] = bfh(v - bf2f(hh[j]));
    }
    *(short8*)&H[dst] = *(const short8*)hh;
    *(short8*)&L[dst] = *(const short8*)ll;
}

// ---------- LayerNorm + concat, split to hi/lo; also seed z into X1/X2 ----------
__global__ __launch_bounds__(256) void k_ln_concat2(
    const float* __restrict__ z, const float* __restrict__ c,
    const float* __restrict__ g, const float* __restrict__ bt,
    unsigned short* __restrict__ X0h, unsigned short* __restrict__ X0l,
    unsigned short* __restrict__ X1h, unsigned short* __restrict__ X1l,
    unsigned short* __restrict__ X2h, unsigned short* __restrict__ X2l)
{
    int gid = blockIdx.x * 256 + threadIdx.x;
    int row = gid >> 6;
    int l = threadIdx.x & 63;
    if (row >= B_) return;
    const float* cr = c + (size_t)row * CIN;
    float v0 = cr[l], v1 = cr[l + 64];
    float s = v0 + v1;
    #pragma unroll
    for (int o = 32; o; o >>= 1) s += __shfl_xor(s, o);
    float mean = s * (1.0f / 128.0f);
    float d0 = v0 - mean, d1 = v1 - mean;
    float q = d0 * d0 + d1 * d1;
    #pragma unroll
    for (int o = 32; o; o >>= 1) q += __shfl_xor(q, o);
    float rstd = rsqrtf(q * (1.0f / 128.0f) + 1e-5f);
    float y0 = d0 * rstd * g[l] + bt[l];
    float y1 = d1 * rstd * g[l + 64] + bt[l + 64];
    size_t r0 = (size_t)row * IN0;
    unsigned short h0 = bfh(y0), lo0 = bfh(y0 - bf2f(h0));
    unsigned short h1 = bfh(y1), lo1 = bfh(y1 - bf2f(h1));
    X0h[r0 + 32 + l] = h0; X0l[r0 + 32 + l] = lo0;
    X0h[r0 + 96 + l] = h1; X0l[r0 + 96 + l] = lo1;
    if (l < LATENT) {
        float zv = z[(size_t)row * LATENT + l];
        unsigned short zh = bfh(zv), zl = bfh(zv - bf2f(zh));
        X0h[r0 + l] = zh; X0l[r0 + l] = zl;
        size_t r1 = (size_t)row * INTER;
        X1h[r1 + l] = zh; X1l[r1 + l] = zl;
        X2h[r1 + l] = zh; X2l[r1 + l] = zl;
    }
}

// ---------- MoE v6: K-split, 128-thr blocks, 8 blocks/CU, A in regs, Abel fold ----------
// grid 2048: bid>>10 = K-half, (bid&1023): brow = (b>>3)*64, bn = (b&7)*32.
// Wave (2/block) = 32 rows x 32 cols (acc 2mf x 2nf). A frags global->VGPR,
// reg-double-buffered (prefetch at e==4). B: 3x4KB LDS ring, 2 gloads/lane/phase.
// ks-outer / e-inner; Abel fold accT += (cf_e - cf_{e+1}) * accW each phase;
// accW reset at e==0; bias folded at ks==0 of half 0 only. Writes fp32 partial.
template<int KTOT, int KS_Ha, int KS_Hb, int KOFS_B>
__global__ __launch_bounds__(128, 4) void k_moe_ks(
    const unsigned short* __restrict__ Ah, const unsigned short* __restrict__ Al,
    const unsigned short* __restrict__ Bh, const unsigned short* __restrict__ Bl,
    const float* __restrict__ bias,   // [8][256]
    const float* __restrict__ coeff,  // [B][8]
    float* __restrict__ Pa, float* __restrict__ Pb)
{
    __shared__ __align__(16) char sB[3][4096];   // per buf: hi[g0|g1] 2KB, lo[g0|g1] 2KB
    __shared__ float cfd_s[8][64];
    __shared__ float bias_s[8][32];

    const int tid = threadIdx.x, wid = tid >> 6, l = tid & 63;
    const int half = blockIdx.x >> 10, b = blockIdx.x & 1023;
    const int brow = (b >> 3) * 64, bn = (b & 7) * 32;
    const int KS   = half ? KS_Hb : KS_Ha;
    const int kofs = half ? KOFS_B : 0;
    float* outP = half ? Pb : Pa;

    for (int idx = tid; idx < 512; idx += 128) {
        int r = idx >> 3, e = idx & 7;
        float v = coeff[(size_t)(brow + r) * 8 + e];
        float w = (e < 7) ? coeff[(size_t)(brow + r) * 8 + e + 1] : 0.0f;
        cfd_s[e][r] = v - w;
    }
    for (int idx = tid; idx < 256; idx += 128)
        bias_s[idx >> 5][idx & 31] = bias[(idx >> 5) * HID + bn + (idx & 31)];

    // A frag sources (MFMA layout: row = l&15, k-chunk = l>>4)
    const unsigned short* Afh = Ah + (size_t)(brow + wid * 32 + (l & 15)) * KTOT + kofs + (l >> 4) * 8;
    const unsigned short* Afl = Al + (size_t)(brow + wid * 32 + (l & 15)) * KTOT + kofs + (l >> 4) * 8;
    i32x4 ah0 = *(const i32x4*)(Afh);
    i32x4 ah1 = *(const i32x4*)(Afh + (size_t)16 * KTOT);
    i32x4 al0 = *(const i32x4*)(Afl);
    i32x4 al1 = *(const i32x4*)(Afl + (size_t)16 * KTOT);

    // B staging: wave wid stages hi-group-wid and lo-group-wid (2 gloads/lane)
    const int swz = (((l & 3) ^ ((l >> 3) & 3)) << 3);
    const int rq  = l >> 2;
    const unsigned short* sB0 = Bh + (size_t)(bn + wid * 16 + rq) * KTOT + kofs + swz;
    const unsigned short* sB1 = Bl + (size_t)(bn + wid * 16 + rq) * KTOT + kofs + swz;
    auto stageB = [&](int e_, int ks_, int bi) {
        const size_t off = (size_t)e_ * HID * KTOT + ks_ * 32;
        gload16(sB0 + off, sB[bi] + wid * 1024);
        gload16(sB1 + off, sB[bi] + 2048 + wid * 1024);
    };

    stageB(0, 0, 0);
    stageB(1, 0, 1);
    __syncthreads();   // drain A regs + bufs 0,1 + cfd/bias
    asm volatile("" : "+v"(ah0), "+v"(ah1), "+v"(al0), "+v"(al1));

    const int rdo = ((l & 15) << 6) + (((l >> 4) ^ ((l >> 1) & 3)) << 4);
    f32x4 accW[2][2], accT[2][2];
    #pragma unroll
    for (int mf = 0; mf < 2; ++mf)
        #pragma unroll
        for (int nf = 0; nf < 2; ++nf) accT[mf][nf] = (f32x4){0.f, 0.f, 0.f, 0.f};

    i32x4 nh0, nh1, nl0, nl1;
    int bcur = 0;
    for (int ks = 0; ks < KS; ++ks) {
        const bool lastg = (ks + 1 >= KS);
        #pragma unroll
        for (int e = 0; e < 8; ++e) {
            // ---- wait (exact FIFO counts: B=2/phase, A-regs 4 @ e==4) ----
            if (e == 7)            { if (lastg) { asm volatile("s_waitcnt vmcnt(0)" ::: "memory"); }
                                     else       { asm volatile("s_waitcnt vmcnt(2)" ::: "memory"); } }
            else if (e == 5 || e == 6) { if (lastg) { asm volatile("s_waitcnt vmcnt(2)" ::: "memory"); }
                                         else       { asm volatile("s_waitcnt vmcnt(6)" ::: "memory"); } }
            else                   { asm volatile("s_waitcnt vmcnt(2)" ::: "memory"); }
            __builtin_amdgcn_s_barrier();
            // ---- issue next stages (B first, then A prefetch) ----
            {
                const int e2 = (e < 6) ? e + 2 : e - 6;
                const int k2 = (e < 6) ? ks : ks + 1;
                if (k2 < KS) { int bi = bcur + 2; if (bi >= 3) bi -= 3; stageB(e2, k2, bi); }
            }
            if (e == 4 && !lastg) {
                nh0 = *(const i32x4*)(Afh + (ks + 1) * 32);
                nh1 = *(const i32x4*)(Afh + (size_t)16 * KTOT + (ks + 1) * 32);
                nl0 = *(const i32x4*)(Afl + (ks + 1) * 32);
                nl1 = *(const i32x4*)(Afl + (size_t)16 * KTOT + (ks + 1) * 32);
            }
            __builtin_amdgcn_sched_barrier(0);

            const char* bp = sB[bcur];
            short8 bh0 = *(const short8*)(bp + rdo);
            short8 bh1 = *(const short8*)(bp + 1024 + rdo);
            short8 bl0 = *(const short8*)(bp + 2048 + rdo);
            short8 bl1 = *(const short8*)(bp + 3072 + rdo);

            if (e == 0) {
                #pragma unroll
                for (int mf = 0; mf < 2; ++mf)
                    #pragma unroll
                    for (int nf = 0; nf < 2; ++nf) accW[mf][nf] = (f32x4){0.f, 0.f, 0.f, 0.f};
            }
            if (half == 0 && ks == 0) {   // bias enters once, telescoped by the fold
                #pragma unroll
                for (int nf = 0; nf < 2; ++nf) {
                    float bv = bias_s[e][nf * 16 + (l & 15)];
                    #pragma unroll
                    for (int mf = 0; mf < 2; ++mf)
                        #pragma unroll
                        for (int r = 0; r < 4; ++r) accW[mf][nf][r] += bv;
                }
            }
            __builtin_amdgcn_s_setprio(1);
            accW[0][0] = __builtin_amdgcn_mfma_f32_16x16x32_bf16(as_s8(ah0), bh0, accW[0][0], 0, 0, 0);
            accW[0][0] = __builtin_amdgcn_mfma_f32_16x16x32_bf16(as_s8(ah0), bl0, accW[0][0], 0, 0, 0);
            accW[0][0] = __builtin_amdgcn_mfma_f32_16x16x32_bf16(as_s8(al0), bh0, accW[0][0], 0, 0, 0);
            accW[0][1] = __builtin_amdgcn_mfma_f32_16x16x32_bf16(as_s8(ah0), bh1, accW[0][1], 0, 0, 0);
            accW[0][1] = __builtin_amdgcn_mfma_f32_16x16x32_bf16(as_s8(ah0), bl1, accW[0][1], 0, 0, 0);
            accW[0][1] = __builtin_amdgcn_mfma_f32_16x16x32_bf16(as_s8(al0), bh1, accW[0][1], 0, 0, 0);
            accW[1][0] = __builtin_amdgcn_mfma_f32_16x16x32_bf16(as_s8(ah1), bh0, accW[1][0], 0, 0, 0);
            accW[1][0] = __builtin_amdgcn_mfma_f32_16x16x32_bf16(as_s8(ah1), bl0, accW[1][0], 0, 0, 0);
            accW[1][0] = __builtin_amdgcn_mfma_f32_16x16x32_bf16(as_s8(al1), bh0, accW[1][0], 0, 0, 0);
            accW[1][1] = __builtin_amdgcn_mfma_f32_16x16x32_bf16(as_s8(ah1), bh1, accW[1][1], 0, 0, 0);
            accW[1][1] = __builtin_amdgcn_mfma_f32_16x16x32_bf16(as_s8(ah1), bl1, accW[1][1], 0, 0, 0);
            accW[1][1] = __builtin_amdgcn_mfma_f32_16x16x32_bf16(as_s8(al1), bh1, accW[1][1], 0, 0, 0);
            __builtin_amdgcn_s_setprio(0);

            // Abel fold
            f32x4 cv0 = *(const f32x4*)&cfd_s[e][wid * 32 + ((l >> 4) << 2)];
            f32x4 cv1 = *(const f32x4*)&cfd_s[e][wid * 32 + 16 + ((l >> 4) << 2)];
            #pragma unroll
            for (int nf = 0; nf < 2; ++nf)
                #pragma unroll
                for (int r = 0; r < 4; ++r) {
                    accT[0][nf][r] += cv0[r] * accW[0][nf][r];
                    accT[1][nf][r] += cv1[r] * accW[1][nf][r];
                }
            if (++bcur == 3) bcur = 0;
        }
        if (!lastg) { ah0 = nh0; ah1 = nh1; al0 = nl0; al1 = nl1; }
    }

    // fp32 partial store
    #pragma unroll
    for (int mf = 0; mf < 2; ++mf)
        #pragma unroll
        for (int nf = 0; nf < 2; ++nf)
            #pragma unroll
            for (int r = 0; r < 4; ++r) {
                const int row = brow + wid * 32 + mf * 16 + ((l >> 4) << 2) + r;
                const int col = bn + nf * 16 + (l & 15);
                outP[(size_t)row * HID + col] = accT[mf][nf][r];
            }
}

// ---------- reduce halves: ELU(Pa+Pb) -> hi/lo bf16 at INTER stride ----------
__global__ __launch_bounds__(256) void k_red(
    const float* __restrict__ Pa, const float* __restrict__ Pb,
    unsigned short* __restrict__ outH, unsigned short* __restrict__ outL)
{
    int id = blockIdx.x * 256 + threadIdx.x;
    int base = id * 4;
    if (base >= B_ * HID) return;
    f32x4 a = *(const f32x4*)&Pa[base];
    f32x4 bsum = *(const f32x4*)&Pb[base];
    int row = base >> 8, col = base & 255;
    unsigned short h4[4], l4[4];
    #pragma unroll
    for (int j = 0; j < 4; ++j) {
        float ev = elu1(a[j] + bsum[j]);
        h4[j] = bfh(ev);
        l4[j] = bfh(ev - bf2f(h4[j]));
    }
    size_t o = (size_t)row * INTER + 32 + col;
    *(short4v*)&outH[o] = *(const short4v*)h4;
    *(short4v*)&outL[o] = *(const short4v*)l4;
}

// ---------- small GEMM: 64-row / 4-wave, weight-stationary, no K-loop barriers ----------
template<int KS, int NCOL, int OUTM, int SOUT, int OFS>
__global__ __launch_bounds__(256, 2) void k_small64(
    const unsigned short* __restrict__ Ah, const unsigned short* __restrict__ Al,
    const unsigned short* __restrict__ Bh, const unsigned short* __restrict__ Bl,
    const float* __restrict__ bias,
    float* __restrict__ outF, unsigned short* __restrict__ outH,
    unsigned short* __restrict__ outL)
{
    constexpr int K  = KS * 32;
    constexpr int NG = NCOL / 16;
    constexpr int CT = 128 / NCOL;
    __shared__ __align__(16) char smem[KS * NG * 2048];

    const int tid = threadIdx.x, wid = tid >> 6, l = tid & 63;
    const int brow = (blockIdx.x / CT) * 64 + wid * 16;
    const int bn   = (blockIdx.x % CT) * NCOL;

    const unsigned short* Arh = Ah + (size_t)(brow + (l & 15)) * K + (l >> 4) * 8;
    const unsigned short* Arl = Al + (size_t)(brow + (l & 15)) * K + (l >> 4) * 8;
    i32x4 ah_[KS], al_[KS];
    #pragma unroll
    for (int ks = 0; ks < KS; ++ks) {
        ah_[ks] = *(const i32x4*)(Arh + ks * 32);
        al_[ks] = *(const i32x4*)(Arl + ks * 32);
    }

    const int swz = (((l & 3) ^ ((l >> 3) & 3)) << 3);
    const int rq  = l >> 2;
    #pragma unroll
    for (int p = 0; p < KS * NG; ++p) {
        if ((p & 3) != wid) continue;
        const int ks = p / NG, g = p % NG;
        const size_t so = (size_t)(bn + g * 16 + rq) * K + ks * 32 + swz;
        gload16(Bh + so, smem + p * 2048);
        gload16(Bl + so, smem + p * 2048 + 1024);
    }
    __syncthreads();

    const int rdo = ((l & 15) << 6) + (((l >> 4) ^ ((l >> 1) & 3)) << 4);
    f32x4 acc[NG];
    #pragma unroll
    for (int nf = 0; nf < NG; ++nf) {
        float bv = bias[bn + nf * 16 + (l & 15)];
        acc[nf] = (f32x4){bv, bv, bv, bv};
    }
    #pragma unroll
    for (int ks = 0; ks < KS; ++ks)
        #pragma unroll
        for (int nf = 0; nf < NG; ++nf) {
            const char* bp = smem + (size_t)(ks * NG + nf) * 2048;
            short8 bh = *(const short8*)(bp + rdo);
            short8 bl = *(const short8*)(bp + 1024 + rdo);
            acc[nf] = __builtin_amdgcn_mfma_f32_16x16x32_bf16(as_s8(ah_[ks]), bh, acc[nf], 0, 0, 0);
            acc[nf] = __builtin_amdgcn_mfma_f32_16x16x32_bf16(as_s8(ah_[ks]), bl, acc[nf], 0, 0, 0);
            acc[nf] = __builtin_amdgcn_mfma_f32_16x16x32_bf16(as_s8(al_[ks]), bh, acc[nf], 0, 0, 0);
        }

    #pragma unroll
    for (int nf = 0; nf < NG; ++nf)
        #pragma unroll
        for (int r = 0; r < 4; ++r) {
            const int row = brow + ((l >> 4) << 2) + r;
            const int col = bn + nf * 16 + (l & 15);
            size_t o = (size_t)row * SOUT + OFS + col;
            float v = acc[nf][r];
            if (OUTM == 0) {
                outF[o] = v;
            } else if (OUTM == 2) {
                outF[o] = elu1(v);
            } else {
                float ev = elu1(v);
                unsigned short h = bfh(ev);
                unsigned short lo = bfh(ev - bf2f(h));
                outH[o] = h; outL[o] = lo;
            }
        }
}

// ---------- gate output layer + softmax over 8 experts (one wave/row) ----------
__global__ __launch_bounds__(256) void k_gate_out(
    const float* __restrict__ G2, const float* __restrict__ g2w,
    const float* __restrict__ g2b, float* __restrict__ coeff)
{
    __shared__ float wt[NE][GH];
    int tid = threadIdx.x;
    for (int idx = tid; idx < GH * NE; idx += 256) {
        int k = idx >> 3, e = idx & 7;
        wt[e][k] = g2w[idx];
    }
    __syncthreads();
    int row  = (blockIdx.x * 256 + tid) >> 6;
    int lane = tid & 63;
    if (row >= B_) return;
    float a0 = G2[(size_t)row * GH + lane];
    float a1 = G2[(size_t)row * GH + 64 + lane];
    float p[NE];
    #pragma unroll
    for (int e = 0; e < NE; ++e)
        p[e] = a0 * wt[e][lane] + a1 * wt[e][lane + 64];
    #pragma unroll
    for (int o = 32; o; o >>= 1) {
        #pragma unroll
        for (int e = 0; e < NE; ++e) p[e] += __shfl_xor(p[e], o);
    }
    float mx = -1e30f;
    #pragma unroll
    for (int e = 0; e < NE; ++e) { p[e] += g2b[e]; mx = fmaxf(mx, p[e]); }
    float s = 0.0f;
    #pragma unroll
    for (int e = 0; e < NE; ++e) { p[e] = expf(p[e] - mx); s += p[e]; }
    float inv = 1.0f / s;
    if (lane == 0) {
        #pragma unroll
        for (int e = 0; e < NE; ++e) coeff[(size_t)row * NE + e] = p[e] * inv;
    }
}

// ---------- final mix: out[b,o] = sum_e cf[b,e] * P[b, e*16+o] ----------
__global__ __launch_bounds__(256) void k_mix(
    const float* __restrict__ P, const float* __restrict__ cf, float* __restrict__ out)
{
    int id = blockIdx.x * 256 + threadIdx.x;
    if (id >= B_ * ACTD) return;
    int b = id >> 4, o = id & 15;
    const float* pr = P + (size_t)b * 128 + o;
    const float* cr = cf + (size_t)b * 8;
    float s = 0.f;
    #pragma unroll
    for (int e = 0; e < 8; ++e) s += cr[e] * pr[e * 16];
    out[id] = s;
}

extern "C" void kernel_launch(void* const* d_in, const int* in_sizes, int n_in,
                              void* d_out, int out_size, void* d_ws, size_t ws_size,
                              hipStream_t stream)
{
    (void)in_sizes; (void)n_in; (void)out_size; (void)ws_size;
    const float* z   = (const float*)d_in[0];
    const float* c   = (const float*)d_in[1];
    const float* w0  = (const float*)d_in[2];
    const float* b0  = (const float*)d_in[3];
    const float* w1  = (const float*)d_in[4];
    const float* b1  = (const float*)d_in[5];
    const float* w2  = (const float*)d_in[6];
    const float* b2  = (const float*)d_in[7];
    const float* g0w = (const float*)d_in[8];
    const float* g0b = (const float*)d_in[9];
    const float* g1w = (const float*)d_in[10];
    const float* g1b = (const float*)d_in[11];
    const float* g2w = (const float*)d_in[12];
    const float* g2b = (const float*)d_in[13];
    const float* lng = (const float*)d_in[14];
    const float* lnb = (const float*)d_in[15];
    float* out = (float*)d_out;

    char* p = (char*)d_ws;
    auto alloc = [&](size_t n) { char* r = p; p += (n + 255) & ~(size_t)255; return r; };
    unsigned short* X0h = (unsigned short*)alloc((size_t)B_ * IN0 * 2);
    unsigned short* X0l = (unsigned short*)alloc((size_t)B_ * IN0 * 2);
    unsigned short* X1h = (unsigned short*)alloc((size_t)B_ * INTER * 2);
    unsigned short* X1l = (unsigned short*)alloc((size_t)B_ * INTER * 2);
    unsigned short* X2h = (unsigned short*)alloc((size_t)B_ * INTER * 2);
    unsigned short* X2l = (unsigned short*)alloc((size_t)B_ * INTER * 2);
    unsigned short* G1h = (unsigned short*)alloc((size_t)B_ * GH * 2);
    unsigned short* G1l = (unsigned short*)alloc((size_t)B_ * GH * 2);
    float* G2f = (float*)alloc((size_t)B_ * GH * 4);      // reused as P2 after gate_out
    float* cf  = (float*)alloc((size_t)B_ * NE * 4);
    float* Pa  = (float*)alloc((size_t)B_ * HID * 4);
    float* Pb  = (float*)alloc((size_t)B_ * HID * 4);
    unsigned short* T0h = (unsigned short*)alloc((size_t)NE * IN0 * HID * 2);
    unsigned short* T0l = (unsigned short*)alloc((size_t)NE * IN0 * HID * 2);
    unsigned short* T1h = (unsigned short*)alloc((size_t)NE * INTER * HID * 2);
    unsigned short* T1l = (unsigned short*)alloc((size_t)NE * INTER * HID * 2);
    unsigned short* T2h = (unsigned short*)alloc((size_t)NE * INTER * ACTD * 2);
    unsigned short* T2l = (unsigned short*)alloc((size_t)NE * INTER * ACTD * 2);
    unsigned short* G0Th = (unsigned short*)alloc((size_t)IN0 * GH * 2);
    unsigned short* G0Tl = (unsigned short*)alloc((size_t)IN0 * GH * 2);
    unsigned short* G1Th = (unsigned short*)alloc((size_t)GH * GH * 2);
    unsigned short* G1Tl = (unsigned short*)alloc((size_t)GH * GH * 2);
    float* P2 = G2f;

    k_prep_g<<<dim3(484), dim3(256), 0, stream>>>(w0, w1, w2, g0w, g1w,
        T0h, T0l, T1h, T1l, T2h, T2l, G0Th, G0Tl, G1Th, G1Tl);
    k_ln_concat2<<<dim3(B_ / 4), dim3(256), 0, stream>>>(z, c, lng, lnb,
        X0h, X0l, X1h, X1l, X2h, X2l);

    // gate MLP: X0 -> G1 (bf16 hi/lo) -> G2f (fp32+elu) -> coeff
    k_small64<5, 64, 1, 128, 0><<<dim3(256), dim3(256), 0, stream>>>(
        X0h, X0l, G0Th, G0Tl, g0b, nullptr, G1h, G1l);
    k_small64<4, 64, 2, 128, 0><<<dim3(256), dim3(256), 0, stream>>>(
        G1h, G1l, G1Th, G1Tl, g1b, G2f, nullptr, nullptr);
    k_gate_out<<<dim3(B_ / 4), dim3(256), 0, stream>>>(G2f, g2w, g2b, cf);

    // expert layers: K-split TLP kernels + reduce
    k_moe_ks<160, 3, 2, 96><<<dim3(2048), dim3(128), 0, stream>>>(
        X0h, X0l, T0h, T0l, b0, cf, Pa, Pb);
    k_red<<<dim3(B_ * HID / 1024), dim3(256), 0, stream>>>(Pa, Pb, X1h, X1l);
    k_moe_ks<288, 5, 4, 160><<<dim3(2048), dim3(128), 0, stream>>>(
        X1h, X1l, T1h, T1l, b1, cf, Pa, Pb);
    k_red<<<dim3(B_ * HID / 1024), dim3(256), 0, stream>>>(Pa, Pb, X2h, X2l);
    // final layer as plain GEMM over N = E*16 = 128, then coeff-mix
    k_small64<9, 32, 0, 128, 0><<<dim3(512), dim3(256), 0, stream>>>(
        X2h, X2l, T2h, T2l, b2, P2, nullptr, nullptr);
    k_mix<<<dim3(B_ * ACTD / 256), dim3(256), 0, stream>>>(P2, cf, out);
}

// Round 11
// 109.665 us; speedup vs baseline: 3.4957x; 3.4957x over previous
//
#include <hip/hip_runtime.h>
#include <hip/hip_bf16.h>
#include <math.h>

#define B_     8192
#define LATENT 32
#define CIN    128
#define HID    256
#define ACTD   16
#define NE     8
#define GH     128
#define IN0    160   // LATENT + CIN
#define INTER  288   // HID + LATENT

typedef __attribute__((ext_vector_type(8))) short short8;
typedef __attribute__((ext_vector_type(4))) float f32x4;
typedef __attribute__((ext_vector_type(4))) int   i32x4;

__device__ __forceinline__ float elu1(float x) { return x > 0.0f ? x : expm1f(x); }

__device__ __forceinline__ unsigned short bfh(float v) {
    __hip_bfloat16 b = __float2bfloat16(v);
    return *reinterpret_cast<unsigned short*>(&b);
}
__device__ __forceinline__ float bf2f(unsigned short u) {
    __hip_bfloat16 b;
    *reinterpret_cast<unsigned short*>(&b) = u;
    return __bfloat162float(b);
}
__device__ __forceinline__ void gload16(const unsigned short* g, const char* lds) {
    __builtin_amdgcn_global_load_lds((const __attribute__((address_space(1))) void*)g,
                                     (__attribute__((address_space(3))) void*)lds, 16, 0, 0);
}
__device__ __forceinline__ short8 as_s8(i32x4 v) {
    union U { i32x4 a; short8 b; } u; u.a = v; return u.b;
}

// ---------- prep (gather form): coalesced short8 writes, strided reads ----------
__global__ __launch_bounds__(256) void k_prep_g(
    const float* __restrict__ w0, const float* __restrict__ w1, const float* __restrict__ w2,
    const float* __restrict__ g0w, const float* __restrict__ g1w,
    unsigned short* __restrict__ T0h, unsigned short* __restrict__ T0l,
    unsigned short* __restrict__ T1h, unsigned short* __restrict__ T1l,
    unsigned short* __restrict__ T2h, unsigned short* __restrict__ T2l,
    unsigned short* __restrict__ G0h, unsigned short* __restrict__ G0l,
    unsigned short* __restrict__ G1h, unsigned short* __restrict__ G1l)
{
    int g = blockIdx.x * 256 + threadIdx.x;
    const float* src; int stride; size_t dst; unsigned short *H, *L;
    if (g < 40960) {                       // T0: [8][160][256] -> [8*256][160]
        int e = g / 5120, r = g % 5120, o = r / 20, i0 = (r % 20) * 8;
        src = w0 + ((size_t)e * 160 + i0) * 256 + o; stride = 256;
        dst = ((size_t)e * 256 + o) * 160 + i0; H = T0h; L = T0l;
    } else if (g < 114688) {               // T1: [8][288][256] -> [8*256][288]
        int t = g - 40960;
        int e = t / 9216, r = t % 9216, o = r / 36, i0 = (r % 36) * 8;
        src = w1 + ((size_t)e * 288 + i0) * 256 + o; stride = 256;
        dst = ((size_t)e * 256 + o) * 288 + i0; H = T1h; L = T1l;
    } else if (g < 119296) {               // T2: [8][288][16] -> [8*16][288]
        int t = g - 114688;
        int e = t / 576, r = t % 576, o = r / 36, i0 = (r % 36) * 8;
        src = w2 + ((size_t)e * 288 + i0) * 16 + o; stride = 16;
        dst = ((size_t)e * 16 + o) * 288 + i0; H = T2h; L = T2l;
    } else if (g < 121856) {               // G0: [160][128] -> [128][160]
        int t = g - 119296;
        int o = t / 20, i0 = (t % 20) * 8;
        src = g0w + (size_t)i0 * 128 + o; stride = 128;
        dst = (size_t)o * 160 + i0; H = G0h; L = G0l;
    } else if (g < 123904) {               // G1: [128][128] -> [128][128]
        int t = g - 121856;
        int o = t / 16, i0 = (t % 16) * 8;
        src = g1w + (size_t)i0 * 128 + o; stride = 128;
        dst = (size_t)o * 128 + i0; H = G1h; L = G1l;
    } else return;
    unsigned short hh[8], ll[8];
    #pragma unroll
    for (int j = 0; j < 8; ++j) {
        float v = src[(size_t)j * stride];
        hh[j] = bfh(v);
        ll[j] = bfh(v - bf2f(hh[j]));
    }
    *(short8*)&H[dst] = *(const short8*)hh;
    *(short8*)&L[dst] = *(const short8*)ll;
}

// ---------- LayerNorm + concat, split to hi/lo; also seed z into X1/X2 ----------
__global__ __launch_bounds__(256) void k_ln_concat2(
    const float* __restrict__ z, const float* __restrict__ c,
    const float* __restrict__ g, const float* __restrict__ bt,
    unsigned short* __restrict__ X0h, unsigned short* __restrict__ X0l,
    unsigned short* __restrict__ X1h, unsigned short* __restrict__ X1l,
    unsigned short* __restrict__ X2h, unsigned short* __restrict__ X2l)
{
    int gid = blockIdx.x * 256 + threadIdx.x;
    int row = gid >> 6;
    int l = threadIdx.x & 63;
    if (row >= B_) return;
    const float* cr = c + (size_t)row * CIN;
    float v0 = cr[l], v1 = cr[l + 64];
    float s = v0 + v1;
    #pragma unroll
    for (int o = 32; o; o >>= 1) s += __shfl_xor(s, o);
    float mean = s * (1.0f / 128.0f);
    float d0 = v0 - mean, d1 = v1 - mean;
    float q = d0 * d0 + d1 * d1;
    #pragma unroll
    for (int o = 32; o; o >>= 1) q += __shfl_xor(q, o);
    float rstd = rsqrtf(q * (1.0f / 128.0f) + 1e-5f);
    float y0 = d0 * rstd * g[l] + bt[l];
    float y1 = d1 * rstd * g[l + 64] + bt[l + 64];
    size_t r0 = (size_t)row * IN0;
    unsigned short h0 = bfh(y0), lo0 = bfh(y0 - bf2f(h0));
    unsigned short h1 = bfh(y1), lo1 = bfh(y1 - bf2f(h1));
    X0h[r0 + 32 + l] = h0; X0l[r0 + 32 + l] = lo0;
    X0h[r0 + 96 + l] = h1; X0l[r0 + 96 + l] = lo1;
    if (l < LATENT) {
        float zv = z[(size_t)row * LATENT + l];
        unsigned short zh = bfh(zv), zl = bfh(zv - bf2f(zh));
        X0h[r0 + l] = zh; X0l[r0 + l] = zl;
        size_t r1 = (size_t)row * INTER;
        X1h[r1 + l] = zh; X1l[r1 + l] = zl;
        X2h[r1 + l] = zh; X2l[r1 + l] = zl;
    }
}

// ---------- MoE layer (r6 structure, SINGLE-buffered -> 3 blocks/CU) ----------
// Block: 256 thr / 4 waves. Tile: 64 rows x 32 cols. Wave w computes experts
// 2w, 2w+1 over the FULL tile (acc[2][4mf][2nf]). Per 32-k phase: one 40KB
// stage region (A 8KB + B 32KB); phase = [vmcnt(0)+bar] reads+48 MFMA
// [lgkmcnt(0)+bar] stage(t+1). 43KB LDS -> 3 blocks/CU; inter-block overlap
// hides the exposed stage latency (m97/m114 mechanism).
template<int KS>
__global__ __launch_bounds__(256, 3) void k_moe_epar(
    const unsigned short* __restrict__ Ah, const unsigned short* __restrict__ Al,
    const unsigned short* __restrict__ Bh, const unsigned short* __restrict__ Bl,
    const float* __restrict__ bias,   // [8][256]
    const float* __restrict__ coeff,  // [B][8]
    unsigned short* __restrict__ outH, unsigned short* __restrict__ outL)
{
    constexpr int K = KS * 32;
    __shared__ __align__(16) char smem[43008];   // stage 40KB + cf 2KB

    const int tid = threadIdx.x, wid = tid >> 6, l = tid & 63;
    const int brow = (blockIdx.x >> 3) * 64;
    const int bn   = (blockIdx.x & 7) * 32;      // each XCD -> one col slice

    // cf table -> LDS (persistent at smem+40960; covered by prologue sync)
    float* cfl = (float*)(smem + 40960);         // [64][8]
    if (tid < 128) {
        f32x4 v = *(const f32x4*)&coeff[(size_t)(brow + (tid >> 1)) * 8 + (tid & 1) * 4];
        *(f32x4*)&cfl[tid * 4] = v;
    }

    // staging source pointers (16-row units, proven inverse-swizzled source)
    const int swz = (((l & 3) ^ ((l >> 3) & 3)) << 3);
    const int rq  = l >> 2;
    const unsigned short* sA[2];
    sA[0] = Ah + (size_t)(brow + wid * 16 + rq) * K + swz;
    sA[1] = Al + (size_t)(brow + wid * 16 + rq) * K + swz;
    const unsigned short* sB2[2][2];
    #pragma unroll
    for (int e2 = 0; e2 < 2; ++e2) {
        sB2[e2][0] = Bh + (size_t)((2 * wid + e2) * HID + bn + rq) * K + swz;
        sB2[e2][1] = Bl + (size_t)((2 * wid + e2) * HID + bn + rq) * K + swz;
    }

    auto stage = [&](int k0) {   // 10 gload16 per lane into the single buffer
        char* buf = smem;
        #pragma unroll
        for (int h = 0; h < 2; ++h)
            gload16(sA[h] + k0, buf + h * 4096 + wid * 1024);
        #pragma unroll
        for (int e2 = 0; e2 < 2; ++e2)
            #pragma unroll
            for (int h = 0; h < 2; ++h)
                #pragma unroll
                for (int g = 0; g < 2; ++g)
                    gload16(sB2[e2][h] + g * 16 * K + k0,
                            buf + 8192 + (2 * wid + e2) * 4096 + h * 2048 + g * 1024);
    };

    const int rdo = ((l & 15) << 6) + (((l >> 4) ^ ((l >> 1) & 3)) << 4);
    f32x4 acc[2][4][2];
    #pragma unroll
    for (int e2 = 0; e2 < 2; ++e2)
        #pragma unroll
        for (int mf = 0; mf < 4; ++mf)
            #pragma unroll
            for (int nf = 0; nf < 2; ++nf) acc[e2][mf][nf] = (f32x4){0.f, 0.f, 0.f, 0.f};

    stage(0);
    __syncthreads();   // drains prologue stage + cf LDS writes

    for (int t = 0; t < KS; ++t) {
        if (t > 0) {
            asm volatile("s_waitcnt vmcnt(0)" ::: "memory");   // stage(t) landed
            __builtin_amdgcn_s_barrier();
            __builtin_amdgcn_sched_barrier(0);
        }
        const char* buf = smem;
        short8 afh[4], afl[4];
        #pragma unroll
        for (int mf = 0; mf < 4; ++mf) {
            afh[mf] = *(const short8*)(buf + mf * 1024 + rdo);
            afl[mf] = *(const short8*)(buf + 4096 + mf * 1024 + rdo);
        }
        __builtin_amdgcn_s_setprio(1);
        #pragma unroll
        for (int e2 = 0; e2 < 2; ++e2) {
            const char* be = buf + 8192 + (2 * wid + e2) * 4096;
            short8 bh0 = *(const short8*)(be + rdo);
            short8 bh1 = *(const short8*)(be + 1024 + rdo);
            short8 bl0 = *(const short8*)(be + 2048 + rdo);
            short8 bl1 = *(const short8*)(be + 3072 + rdo);
            #pragma unroll
            for (int mf = 0; mf < 4; ++mf) {
                acc[e2][mf][0] = __builtin_amdgcn_mfma_f32_16x16x32_bf16(afh[mf], bh0, acc[e2][mf][0], 0, 0, 0);
                acc[e2][mf][0] = __builtin_amdgcn_mfma_f32_16x16x32_bf16(afh[mf], bl0, acc[e2][mf][0], 0, 0, 0);
                acc[e2][mf][0] = __builtin_amdgcn_mfma_f32_16x16x32_bf16(afl[mf], bh0, acc[e2][mf][0], 0, 0, 0);
                acc[e2][mf][1] = __builtin_amdgcn_mfma_f32_16x16x32_bf16(afh[mf], bh1, acc[e2][mf][1], 0, 0, 0);
                acc[e2][mf][1] = __builtin_amdgcn_mfma_f32_16x16x32_bf16(afh[mf], bl1, acc[e2][mf][1], 0, 0, 0);
                acc[e2][mf][1] = __builtin_amdgcn_mfma_f32_16x16x32_bf16(afl[mf], bh1, acc[e2][mf][1], 0, 0, 0);
            }
        }
        __builtin_amdgcn_s_setprio(0);
        asm volatile("s_waitcnt lgkmcnt(0)" ::: "memory");     // reads retired
        __builtin_amdgcn_sched_barrier(0);
        __builtin_amdgcn_s_barrier();                          // safe to overwrite
        if (t + 1 < KS) stage((t + 1) * 32);
    }

    // ---- epilogue: scale partials with cf, cross-wave reduce via LDS ----
    const int e0 = 2 * wid, e1 = 2 * wid + 1;
    float bv0[2], bv1[2];
    #pragma unroll
    for (int nf = 0; nf < 2; ++nf) {
        bv0[nf] = bias[e0 * HID + bn + nf * 16 + (l & 15)];
        bv1[nf] = bias[e1 * HID + bn + nf * 16 + (l & 15)];
    }
    float* red = (float*)smem;                        // [4][64][36], overlays stage buf
    #pragma unroll
    for (int mf = 0; mf < 4; ++mf) {
        const int rb = mf * 16 + ((l >> 4) << 2);
        #pragma unroll
        for (int r = 0; r < 4; ++r) {
            float c0 = cfl[(rb + r) * 8 + e0];
            float c1 = cfl[(rb + r) * 8 + e1];
            #pragma unroll
            for (int nf = 0; nf < 2; ++nf) {
                float s = (acc[0][mf][nf][r] + bv0[nf]) * c0
                        + (acc[1][mf][nf][r] + bv1[nf]) * c1;
                red[wid * 2304 + (rb + r) * 36 + nf * 16 + (l & 15)] = s;
            }
        }
    }
    __syncthreads();

    const int row = tid >> 2, c0_ = (tid & 3) * 8;
    f32x4 s0 = {0.f, 0.f, 0.f, 0.f}, s1 = {0.f, 0.f, 0.f, 0.f};
    #pragma unroll
    for (int w = 0; w < 4; ++w) {
        s0 += *(const f32x4*)&red[w * 2304 + row * 36 + c0_];
        s1 += *(const f32x4*)&red[w * 2304 + row * 36 + c0_ + 4];
    }
    unsigned short hh[8], ll[8];
    #pragma unroll
    for (int j = 0; j < 4; ++j) {
        float ev = elu1(s0[j]);
        hh[j] = bfh(ev); ll[j] = bfh(ev - bf2f(hh[j]));
        float ev2 = elu1(s1[j]);
        hh[4 + j] = bfh(ev2); ll[4 + j] = bfh(ev2 - bf2f(hh[4 + j]));
    }
    size_t o = (size_t)(brow + row) * INTER + 32 + bn + c0_;
    *(short8*)&outH[o] = *(const short8*)hh;
    *(short8*)&outL[o] = *(const short8*)ll;
}

// ---------- small GEMM: 64-row / 4-wave, weight-stationary, no K-loop barriers ----------
template<int KS, int NCOL, int OUTM, int SOUT, int OFS>
__global__ __launch_bounds__(256, 2) void k_small64(
    const unsigned short* __restrict__ Ah, const unsigned short* __restrict__ Al,
    const unsigned short* __restrict__ Bh, const unsigned short* __restrict__ Bl,
    const float* __restrict__ bias,
    float* __restrict__ outF, unsigned short* __restrict__ outH,
    unsigned short* __restrict__ outL)
{
    constexpr int K  = KS * 32;
    constexpr int NG = NCOL / 16;
    constexpr int CT = 128 / NCOL;
    __shared__ __align__(16) char smem[KS * NG * 2048];

    const int tid = threadIdx.x, wid = tid >> 6, l = tid & 63;
    const int brow = (blockIdx.x / CT) * 64 + wid * 16;
    const int bn   = (blockIdx.x % CT) * NCOL;

    const unsigned short* Arh = Ah + (size_t)(brow + (l & 15)) * K + (l >> 4) * 8;
    const unsigned short* Arl = Al + (size_t)(brow + (l & 15)) * K + (l >> 4) * 8;
    i32x4 ah_[KS], al_[KS];
    #pragma unroll
    for (int ks = 0; ks < KS; ++ks) {
        ah_[ks] = *(const i32x4*)(Arh + ks * 32);
        al_[ks] = *(const i32x4*)(Arl + ks * 32);
    }

    const int swz = (((l & 3) ^ ((l >> 3) & 3)) << 3);
    const int rq  = l >> 2;
    #pragma unroll
    for (int p = 0; p < KS * NG; ++p) {
        if ((p & 3) != wid) continue;
        const int ks = p / NG, g = p % NG;
        const size_t so = (size_t)(bn + g * 16 + rq) * K + ks * 32 + swz;
        gload16(Bh + so, smem + p * 2048);
        gload16(Bl + so, smem + p * 2048 + 1024);
    }
    __syncthreads();

    const int rdo = ((l & 15) << 6) + (((l >> 4) ^ ((l >> 1) & 3)) << 4);
    f32x4 acc[NG];
    #pragma unroll
    for (int nf = 0; nf < NG; ++nf) {
        float bv = bias[bn + nf * 16 + (l & 15)];
        acc[nf] = (f32x4){bv, bv, bv, bv};
    }
    #pragma unroll
    for (int ks = 0; ks < KS; ++ks)
        #pragma unroll
        for (int nf = 0; nf < NG; ++nf) {
            const char* bp = smem + (size_t)(ks * NG + nf) * 2048;
            short8 bh = *(const short8*)(bp + rdo);
            short8 bl = *(const short8*)(bp + 1024 + rdo);
            acc[nf] = __builtin_amdgcn_mfma_f32_16x16x32_bf16(as_s8(ah_[ks]), bh, acc[nf], 0, 0, 0);
            acc[nf] = __builtin_amdgcn_mfma_f32_16x16x32_bf16(as_s8(ah_[ks]), bl, acc[nf], 0, 0, 0);
            acc[nf] = __builtin_amdgcn_mfma_f32_16x16x32_bf16(as_s8(al_[ks]), bh, acc[nf], 0, 0, 0);
        }

    #pragma unroll
    for (int nf = 0; nf < NG; ++nf)
        #pragma unroll
        for (int r = 0; r < 4; ++r) {
            const int row = brow + ((l >> 4) << 2) + r;
            const int col = bn + nf * 16 + (l & 15);
            size_t o = (size_t)row * SOUT + OFS + col;
            float v = acc[nf][r];
            if (OUTM == 0) {
                outF[o] = v;
            } else if (OUTM == 2) {
                outF[o] = elu1(v);
            } else {
                float ev = elu1(v);
                unsigned short h = bfh(ev);
                unsigned short lo = bfh(ev - bf2f(h));
                outH[o] = h; outL[o] = lo;
            }
        }
}

// ---------- gate output layer + softmax over 8 experts (one wave/row) ----------
__global__ __launch_bounds__(256) void k_gate_out(
    const float* __restrict__ G2, const float* __restrict__ g2w,
    const float* __restrict__ g2b, float* __restrict__ coeff)
{
    __shared__ float wt[NE][GH];
    int tid = threadIdx.x;
    for (int idx = tid; idx < GH * NE; idx += 256) {
        int k = idx >> 3, e = idx & 7;
        wt[e][k] = g2w[idx];
    }
    __syncthreads();
    int row  = (blockIdx.x * 256 + tid) >> 6;
    int lane = tid & 63;
    if (row >= B_) return;
    float a0 = G2[(size_t)row * GH + lane];
    float a1 = G2[(size_t)row * GH + 64 + lane];
    float p[NE];
    #pragma unroll
    for (int e = 0; e < NE; ++e)
        p[e] = a0 * wt[e][lane] + a1 * wt[e][lane + 64];
    #pragma unroll
    for (int o = 32; o; o >>= 1) {
        #pragma unroll
        for (int e = 0; e < NE; ++e) p[e] += __shfl_xor(p[e], o);
    }
    float mx = -1e30f;
    #pragma unroll
    for (int e = 0; e < NE; ++e) { p[e] += g2b[e]; mx = fmaxf(mx, p[e]); }
    float s = 0.0f;
    #pragma unroll
    for (int e = 0; e < NE; ++e) { p[e] = expf(p[e] - mx); s += p[e]; }
    float inv = 1.0f / s;
    if (lane == 0) {
        #pragma unroll
        for (int e = 0; e < NE; ++e) coeff[(size_t)row * NE + e] = p[e] * inv;
    }
}

// ---------- final mix: out[b,o] = sum_e cf[b,e] * P[b, e*16+o] ----------
__global__ __launch_bounds__(256) void k_mix(
    const float* __restrict__ P, const float* __restrict__ cf, float* __restrict__ out)
{
    int id = blockIdx.x * 256 + threadIdx.x;
    if (id >= B_ * ACTD) return;
    int b = id >> 4, o = id & 15;
    const float* pr = P + (size_t)b * 128 + o;
    const float* cr = cf + (size_t)b * 8;
    float s = 0.f;
    #pragma unroll
    for (int e = 0; e < 8; ++e) s += cr[e] * pr[e * 16];
    out[id] = s;
}

extern "C" void kernel_launch(void* const* d_in, const int* in_sizes, int n_in,
                              void* d_out, int out_size, void* d_ws, size_t ws_size,
                              hipStream_t stream)
{
    (void)in_sizes; (void)n_in; (void)out_size; (void)ws_size;
    const float* z   = (const float*)d_in[0];
    const float* c   = (const float*)d_in[1];
    const float* w0  = (const float*)d_in[2];
    const float* b0  = (const float*)d_in[3];
    const float* w1  = (const float*)d_in[4];
    const float* b1  = (const float*)d_in[5];
    const float* w2  = (const float*)d_in[6];
    const float* b2  = (const float*)d_in[7];
    const float* g0w = (const float*)d_in[8];
    const float* g0b = (const float*)d_in[9];
    const float* g1w = (const float*)d_in[10];
    const float* g1b = (const float*)d_in[11];
    const float* g2w = (const float*)d_in[12];
    const float* g2b = (const float*)d_in[13];
    const float* lng = (const float*)d_in[14];
    const float* lnb = (const float*)d_in[15];
    float* out = (float*)d_out;

    char* p = (char*)d_ws;
    auto alloc = [&](size_t n) { char* r = p; p += (n + 255) & ~(size_t)255; return r; };
    unsigned short* X0h = (unsigned short*)alloc((size_t)B_ * IN0 * 2);
    unsigned short* X0l = (unsigned short*)alloc((size_t)B_ * IN0 * 2);
    unsigned short* X1h = (unsigned short*)alloc((size_t)B_ * INTER * 2);
    unsigned short* X1l = (unsigned short*)alloc((size_t)B_ * INTER * 2);
    unsigned short* X2h = (unsigned short*)alloc((size_t)B_ * INTER * 2);
    unsigned short* X2l = (unsigned short*)alloc((size_t)B_ * INTER * 2);
    unsigned short* G1h = (unsigned short*)alloc((size_t)B_ * GH * 2);
    unsigned short* G1l = (unsigned short*)alloc((size_t)B_ * GH * 2);
    float* G2f = (float*)alloc((size_t)B_ * GH * 4);      // reused as P2 after gate_out
    float* cf  = (float*)alloc((size_t)B_ * NE * 4);
    unsigned short* T0h = (unsigned short*)alloc((size_t)NE * IN0 * HID * 2);
    unsigned short* T0l = (unsigned short*)alloc((size_t)NE * IN0 * HID * 2);
    unsigned short* T1h = (unsigned short*)alloc((size_t)NE * INTER * HID * 2);
    unsigned short* T1l = (unsigned short*)alloc((size_t)NE * INTER * HID * 2);
    unsigned short* T2h = (unsigned short*)alloc((size_t)NE * INTER * ACTD * 2);
    unsigned short* T2l = (unsigned short*)alloc((size_t)NE * INTER * ACTD * 2);
    unsigned short* G0Th = (unsigned short*)alloc((size_t)IN0 * GH * 2);
    unsigned short* G0Tl = (unsigned short*)alloc((size_t)IN0 * GH * 2);
    unsigned short* G1Th = (unsigned short*)alloc((size_t)GH * GH * 2);
    unsigned short* G1Tl = (unsigned short*)alloc((size_t)GH * GH * 2);
    float* P2 = G2f;

    k_prep_g<<<dim3(484), dim3(256), 0, stream>>>(w0, w1, w2, g0w, g1w,
        T0h, T0l, T1h, T1l, T2h, T2l, G0Th, G0Tl, G1Th, G1Tl);
    k_ln_concat2<<<dim3(B_ / 4), dim3(256), 0, stream>>>(z, c, lng, lnb,
        X0h, X0l, X1h, X1l, X2h, X2l);

    // gate MLP: X0 -> G1 (bf16 hi/lo) -> G2f (fp32+elu) -> coeff
    k_small64<5, 64, 1, 128, 0><<<dim3(256), dim3(256), 0, stream>>>(
        X0h, X0l, G0Th, G0Tl, g0b, nullptr, G1h, G1l);
    k_small64<4, 64, 2, 128, 0><<<dim3(256), dim3(256), 0, stream>>>(
        G1h, G1l, G1Th, G1Tl, g1b, G2f, nullptr, nullptr);
    k_gate_out<<<dim3(B_ / 4), dim3(256), 0, stream>>>(G2f, g2w, g2b, cf);

    // expert layers: expert-parallel waves, single-buffered, 3 blocks/CU
    k_moe_epar<5><<<dim3(1024), dim3(256), 0, stream>>>(
        X0h, X0l, T0h, T0l, b0, cf, X1h, X1l);
    k_moe_epar<9><<<dim3(1024), dim3(256), 0, stream>>>(
        X1h, X1l, T1h, T1l, b1, cf, X2h, X2l);
    // final layer as plain GEMM over N = E*16 = 128, then coeff-mix
    k_small64<9, 32, 0, 128, 0><<<dim3(512), dim3(256), 0, stream>>>(
        X2h, X2l, T2h, T2l, b2, P2, nullptr, nullptr);
    k_mix<<<dim3(B_ * ACTD / 256), dim3(256), 0, stream>>>(P2, cf, out);
}

// Round 12
// 70.558 us; speedup vs baseline: 5.4332x; 1.5543x over previous
//
#include <hip/hip_runtime.h>
#include <math.h>

#define B_     8192
#define LATENT 32
#define CIN    128
#define HID    256
#define ACTD   16
#define NE     8
#define GH     128
#define IN0    160   // LATENT + CIN
#define INTER  288   // HID + LATENT

typedef __attribute__((ext_vector_type(8))) _Float16 half8;
typedef __attribute__((ext_vector_type(4))) float    f32x4;
typedef __attribute__((ext_vector_type(4))) int      i32x4;

__device__ __forceinline__ float elu1(float x) { return x > 0.0f ? x : expm1f(x); }

__device__ __forceinline__ void gload16(const void* g, const char* lds) {
    __builtin_amdgcn_global_load_lds((const __attribute__((address_space(1))) void*)g,
                                     (__attribute__((address_space(3))) void*)lds, 16, 0, 0);
}
__device__ __forceinline__ half8 as_h8(i32x4 v) {
    union U { i32x4 a; half8 b; } u; u.a = v; return u.b;
}

// ---------- prep (gather form): fp16 convert + transpose, coalesced stores ----------
__global__ __launch_bounds__(256) void k_prep_g(
    const float* __restrict__ w0, const float* __restrict__ w1, const float* __restrict__ w2,
    const float* __restrict__ g0w, const float* __restrict__ g1w,
    _Float16* __restrict__ T0, _Float16* __restrict__ T1, _Float16* __restrict__ T2,
    _Float16* __restrict__ G0, _Float16* __restrict__ G1)
{
    int g = blockIdx.x * 256 + threadIdx.x;
    const float* src; int stride; size_t dst; _Float16* H;
    if (g < 40960) {                       // T0: [8][160][256] -> [8*256][160]
        int e = g / 5120, r = g % 5120, o = r / 20, i0 = (r % 20) * 8;
        src = w0 + ((size_t)e * 160 + i0) * 256 + o; stride = 256;
        dst = ((size_t)e * 256 + o) * 160 + i0; H = T0;
    } else if (g < 114688) {               // T1: [8][288][256] -> [8*256][288]
        int t = g - 40960;
        int e = t / 9216, r = t % 9216, o = r / 36, i0 = (r % 36) * 8;
        src = w1 + ((size_t)e * 288 + i0) * 256 + o; stride = 256;
        dst = ((size_t)e * 256 + o) * 288 + i0; H = T1;
    } else if (g < 119296) {               // T2: [8][288][16] -> [8*16][288]
        int t = g - 114688;
        int e = t / 576, r = t % 576, o = r / 36, i0 = (r % 36) * 8;
        src = w2 + ((size_t)e * 288 + i0) * 16 + o; stride = 16;
        dst = ((size_t)e * 16 + o) * 288 + i0; H = T2;
    } else if (g < 121856) {               // G0: [160][128] -> [128][160]
        int t = g - 119296;
        int o = t / 20, i0 = (t % 20) * 8;
        src = g0w + (size_t)i0 * 128 + o; stride = 128;
        dst = (size_t)o * 160 + i0; H = G0;
    } else if (g < 123904) {               // G1: [128][128] -> [128][128]
        int t = g - 121856;
        int o = t / 16, i0 = (t % 16) * 8;
        src = g1w + (size_t)i0 * 128 + o; stride = 128;
        dst = (size_t)o * 128 + i0; H = G1;
    } else return;
    _Float16 hh[8];
    #pragma unroll
    for (int j = 0; j < 8; ++j) hh[j] = (_Float16)src[(size_t)j * stride];
    *(half8*)&H[dst] = *(const half8*)hh;
}

// ---------- LayerNorm + concat to fp16; seed z into X1/X2 ----------
__global__ __launch_bounds__(256) void k_ln_concat2(
    const float* __restrict__ z, const float* __restrict__ c,
    const float* __restrict__ g, const float* __restrict__ bt,
    _Float16* __restrict__ X0, _Float16* __restrict__ X1, _Float16* __restrict__ X2)
{
    int gid = blockIdx.x * 256 + threadIdx.x;
    int row = gid >> 6;
    int l = threadIdx.x & 63;
    if (row >= B_) return;
    const float* cr = c + (size_t)row * CIN;
    float v0 = cr[l], v1 = cr[l + 64];
    float s = v0 + v1;
    #pragma unroll
    for (int o = 32; o; o >>= 1) s += __shfl_xor(s, o);
    float mean = s * (1.0f / 128.0f);
    float d0 = v0 - mean, d1 = v1 - mean;
    float q = d0 * d0 + d1 * d1;
    #pragma unroll
    for (int o = 32; o; o >>= 1) q += __shfl_xor(q, o);
    float rstd = rsqrtf(q * (1.0f / 128.0f) + 1e-5f);
    float y0 = d0 * rstd * g[l] + bt[l];
    float y1 = d1 * rstd * g[l + 64] + bt[l + 64];
    size_t r0 = (size_t)row * IN0;
    X0[r0 + 32 + l] = (_Float16)y0;
    X0[r0 + 96 + l] = (_Float16)y1;
    if (l < LATENT) {
        _Float16 zv = (_Float16)z[(size_t)row * LATENT + l];
        X0[r0 + l] = zv;
        size_t r1 = (size_t)row * INTER;
        X1[r1 + l] = zv;
        X2[r1 + l] = zv;
    }
}

// ---------- MoE layer: fp16, expert-parallel waves, double-buffered, 3 blocks/CU ----------
// Block: 256 thr / 4 waves. Tile 64 rows x 32 cols. Wave w: experts 2w,2w+1
// over the full tile (acc[2][4mf][2nf]). Per 32-k phase: stage {A 4KB + B 16KB}
// (5 gload16/lane) into 2x20KB bufs; 8 ds_read + 16 MFMA/wave; counted vmcnt(5).
// Epilogue: cf-scaled partials cross-wave reduced via LDS.
template<int KS>
__global__ __launch_bounds__(256, 3) void k_moe_epar(
    const _Float16* __restrict__ A, const _Float16* __restrict__ Bw,
    const float* __restrict__ bias,   // [8][256]
    const float* __restrict__ coeff,  // [B][8]
    _Float16* __restrict__ outX)
{
    constexpr int K = KS * 32;
    __shared__ __align__(16) char smem[43008];   // 2 bufs x 20480 + cf 2048

    const int tid = threadIdx.x, wid = tid >> 6, l = tid & 63;
    const int brow = (blockIdx.x >> 3) * 64;
    const int bn   = (blockIdx.x & 7) * 32;      // each XCD -> one col slice

    float* cfl = (float*)(smem + 40960);         // [64][8]
    if (tid < 128) {
        f32x4 v = *(const f32x4*)&coeff[(size_t)(brow + (tid >> 1)) * 8 + (tid & 1) * 4];
        *(f32x4*)&cfl[tid * 4] = v;
    }

    // staging sources (16-row 1KB units, proven inverse-swizzled pattern)
    const int swz = (((l & 3) ^ ((l >> 3) & 3)) << 3);
    const int rq  = l >> 2;
    const _Float16* sA = A + (size_t)(brow + wid * 16 + rq) * K + swz;
    const _Float16* sB2[2][2];
    #pragma unroll
    for (int e2 = 0; e2 < 2; ++e2)
        #pragma unroll
        for (int gg = 0; gg < 2; ++gg)
            sB2[e2][gg] = Bw + (size_t)((2 * wid + e2) * HID + bn + gg * 16 + rq) * K + swz;

    auto stage = [&](int bi, int k0) {   // 5 gload16 per lane
        char* buf = smem + bi * 20480;
        gload16(sA + k0, buf + wid * 1024);
        #pragma unroll
        for (int e2 = 0; e2 < 2; ++e2)
            #pragma unroll
            for (int gg = 0; gg < 2; ++gg)
                gload16(sB2[e2][gg] + k0,
                        buf + 4096 + (2 * wid + e2) * 2048 + gg * 1024);
    };

    const int rdo = ((l & 15) << 6) + (((l >> 4) ^ ((l >> 1) & 3)) << 4);
    f32x4 acc[2][4][2];
    #pragma unroll
    for (int e2 = 0; e2 < 2; ++e2)
        #pragma unroll
        for (int mf = 0; mf < 4; ++mf)
            #pragma unroll
            for (int nf = 0; nf < 2; ++nf) acc[e2][mf][nf] = (f32x4){0.f, 0.f, 0.f, 0.f};

    stage(0, 0);
    if (KS > 1) stage(1, 32);
    __syncthreads();   // full drain: both bufs + cf

    for (int t = 0; t < KS; ++t) {
        const char* buf = smem + (t & 1) * 20480;
        half8 af[4];
        #pragma unroll
        for (int mf = 0; mf < 4; ++mf)
            af[mf] = *(const half8*)(buf + mf * 1024 + rdo);
        __builtin_amdgcn_s_setprio(1);
        #pragma unroll
        for (int e2 = 0; e2 < 2; ++e2) {
            const char* be = buf + 4096 + (2 * wid + e2) * 2048;
            half8 b0 = *(const half8*)(be + rdo);
            half8 b1 = *(const half8*)(be + 1024 + rdo);
            #pragma unroll
            for (int mf = 0; mf < 4; ++mf) {
                acc[e2][mf][0] = __builtin_amdgcn_mfma_f32_16x16x32_f16(af[mf], b0, acc[e2][mf][0], 0, 0, 0);
                acc[e2][mf][1] = __builtin_amdgcn_mfma_f32_16x16x32_f16(af[mf], b1, acc[e2][mf][1], 0, 0, 0);
            }
        }
        __builtin_amdgcn_s_setprio(0);
        asm volatile("s_waitcnt lgkmcnt(0)" ::: "memory");
        __builtin_amdgcn_sched_barrier(0);
        __builtin_amdgcn_s_barrier();                 // reads of buf(t) retired
        if (t + 2 < KS) stage(t & 1, (t + 2) * 32);   // refill the freed buf
        if (t + 1 < KS) {
            if (t + 2 < KS) { asm volatile("s_waitcnt vmcnt(5)" ::: "memory"); }
            else            { asm volatile("s_waitcnt vmcnt(0)" ::: "memory"); }
            __builtin_amdgcn_s_barrier();             // buf(t+1) ready
            __builtin_amdgcn_sched_barrier(0);
        }
    }

    // ---- epilogue: (acc+bias)*cf per wave-expert pair, cross-wave reduce ----
    const int e0 = 2 * wid, e1 = 2 * wid + 1;
    float bv0[2], bv1[2];
    #pragma unroll
    for (int nf = 0; nf < 2; ++nf) {
        bv0[nf] = bias[e0 * HID + bn + nf * 16 + (l & 15)];
        bv1[nf] = bias[e1 * HID + bn + nf * 16 + (l & 15)];
    }
    float* red = (float*)smem;                        // [4][64][36] = 36864 B
    #pragma unroll
    for (int mf = 0; mf < 4; ++mf) {
        const int rb = mf * 16 + ((l >> 4) << 2);
        #pragma unroll
        for (int r = 0; r < 4; ++r) {
            float c0 = cfl[(rb + r) * 8 + e0];
            float c1 = cfl[(rb + r) * 8 + e1];
            #pragma unroll
            for (int nf = 0; nf < 2; ++nf) {
                float s = (acc[0][mf][nf][r] + bv0[nf]) * c0
                        + (acc[1][mf][nf][r] + bv1[nf]) * c1;
                red[wid * 2304 + (rb + r) * 36 + nf * 16 + (l & 15)] = s;
            }
        }
    }
    __syncthreads();

    const int row = tid >> 2, c0_ = (tid & 3) * 8;
    f32x4 s0 = {0.f, 0.f, 0.f, 0.f}, s1 = {0.f, 0.f, 0.f, 0.f};
    #pragma unroll
    for (int w = 0; w < 4; ++w) {
        s0 += *(const f32x4*)&red[w * 2304 + row * 36 + c0_];
        s1 += *(const f32x4*)&red[w * 2304 + row * 36 + c0_ + 4];
    }
    _Float16 hh[8];
    #pragma unroll
    for (int j = 0; j < 4; ++j) {
        hh[j]     = (_Float16)elu1(s0[j]);
        hh[4 + j] = (_Float16)elu1(s1[j]);
    }
    size_t o = (size_t)(brow + row) * INTER + 32 + bn + c0_;
    *(half8*)&outX[o] = *(const half8*)hh;
}

// ---------- small GEMM: fp16, 64-row / 4-wave, weight-stationary ----------
template<int KS, int NCOL, int OUTM, int SOUT, int OFS>
__global__ __launch_bounds__(256, 2) void k_small64(
    const _Float16* __restrict__ A, const _Float16* __restrict__ Bw,
    const float* __restrict__ bias,
    float* __restrict__ outF, _Float16* __restrict__ outX)
{
    constexpr int K  = KS * 32;
    constexpr int NG = NCOL / 16;
    constexpr int CT = 128 / NCOL;
    __shared__ __align__(16) char smem[KS * NG * 1024];

    const int tid = threadIdx.x, wid = tid >> 6, l = tid & 63;
    const int brow = (blockIdx.x / CT) * 64 + wid * 16;
    const int bn   = (blockIdx.x % CT) * NCOL;

    const _Float16* Ar = A + (size_t)(brow + (l & 15)) * K + (l >> 4) * 8;
    i32x4 a_[KS];
    #pragma unroll
    for (int ks = 0; ks < KS; ++ks) a_[ks] = *(const i32x4*)(Ar + ks * 32);

    const int swz = (((l & 3) ^ ((l >> 3) & 3)) << 3);
    const int rq  = l >> 2;
    #pragma unroll
    for (int p = 0; p < KS * NG; ++p) {
        if ((p & 3) != wid) continue;
        const int ks = p / NG, gg = p % NG;
        gload16(Bw + (size_t)(bn + gg * 16 + rq) * K + ks * 32 + swz, smem + p * 1024);
    }
    __syncthreads();

    const int rdo = ((l & 15) << 6) + (((l >> 4) ^ ((l >> 1) & 3)) << 4);
    f32x4 acc[NG];
    #pragma unroll
    for (int nf = 0; nf < NG; ++nf) {
        float bv = bias[bn + nf * 16 + (l & 15)];
        acc[nf] = (f32x4){bv, bv, bv, bv};
    }
    #pragma unroll
    for (int ks = 0; ks < KS; ++ks)
        #pragma unroll
        for (int nf = 0; nf < NG; ++nf) {
            half8 b = *(const half8*)(smem + (size_t)(ks * NG + nf) * 1024 + rdo);
            acc[nf] = __builtin_amdgcn_mfma_f32_16x16x32_f16(as_h8(a_[ks]), b, acc[nf], 0, 0, 0);
        }

    #pragma unroll
    for (int nf = 0; nf < NG; ++nf)
        #pragma unroll
        for (int r = 0; r < 4; ++r) {
            const int row = brow + ((l >> 4) << 2) + r;
            const int col = bn + nf * 16 + (l & 15);
            size_t o = (size_t)row * SOUT + OFS + col;
            float v = acc[nf][r];
            if (OUTM == 0)      outF[o] = v;
            else if (OUTM == 2) outF[o] = elu1(v);
            else                outX[o] = (_Float16)elu1(v);
        }
}

// ---------- gate output layer + softmax over 8 experts (one wave/row) ----------
__global__ __launch_bounds__(256) void k_gate_out(
    const float* __restrict__ G2, const float* __restrict__ g2w,
    const float* __restrict__ g2b, float* __restrict__ coeff)
{
    __shared__ float wt[NE][GH];
    int tid = threadIdx.x;
    for (int idx = tid; idx < GH * NE; idx += 256) {
        int k = idx >> 3, e = idx & 7;
        wt[e][k] = g2w[idx];
    }
    __syncthreads();
    int row  = (blockIdx.x * 256 + tid) >> 6;
    int lane = tid & 63;
    if (row >= B_) return;
    float a0 = G2[(size_t)row * GH + lane];
    float a1 = G2[(size_t)row * GH + 64 + lane];
    float p[NE];
    #pragma unroll
    for (int e = 0; e < NE; ++e)
        p[e] = a0 * wt[e][lane] + a1 * wt[e][lane + 64];
    #pragma unroll
    for (int o = 32; o; o >>= 1) {
        #pragma unroll
        for (int e = 0; e < NE; ++e) p[e] += __shfl_xor(p[e], o);
    }
    float mx = -1e30f;
    #pragma unroll
    for (int e = 0; e < NE; ++e) { p[e] += g2b[e]; mx = fmaxf(mx, p[e]); }
    float s = 0.0f;
    #pragma unroll
    for (int e = 0; e < NE; ++e) { p[e] = expf(p[e] - mx); s += p[e]; }
    float inv = 1.0f / s;
    if (lane == 0) {
        #pragma unroll
        for (int e = 0; e < NE; ++e) coeff[(size_t)row * NE + e] = p[e] * inv;
    }
}

// ---------- final mix: out[b,o] = sum_e cf[b,e] * P[b, e*16+o] ----------
__global__ __launch_bounds__(256) void k_mix(
    const float* __restrict__ P, const float* __restrict__ cf, float* __restrict__ out)
{
    int id = blockIdx.x * 256 + threadIdx.x;
    if (id >= B_ * ACTD) return;
    int b = id >> 4, o = id & 15;
    const float* pr = P + (size_t)b * 128 + o;
    const float* cr = cf + (size_t)b * 8;
    float s = 0.f;
    #pragma unroll
    for (int e = 0; e < 8; ++e) s += cr[e] * pr[e * 16];
    out[id] = s;
}

extern "C" void kernel_launch(void* const* d_in, const int* in_sizes, int n_in,
                              void* d_out, int out_size, void* d_ws, size_t ws_size,
                              hipStream_t stream)
{
    (void)in_sizes; (void)n_in; (void)out_size; (void)ws_size;
    const float* z   = (const float*)d_in[0];
    const float* c   = (const float*)d_in[1];
    const float* w0  = (const float*)d_in[2];
    const float* b0  = (const float*)d_in[3];
    const float* w1  = (const float*)d_in[4];
    const float* b1  = (const float*)d_in[5];
    const float* w2  = (const float*)d_in[6];
    const float* b2  = (const float*)d_in[7];
    const float* g0w = (const float*)d_in[8];
    const float* g0b = (const float*)d_in[9];
    const float* g1w = (const float*)d_in[10];
    const float* g1b = (const float*)d_in[11];
    const float* g2w = (const float*)d_in[12];
    const float* g2b = (const float*)d_in[13];
    const float* lng = (const float*)d_in[14];
    const float* lnb = (const float*)d_in[15];
    float* out = (float*)d_out;

    char* p = (char*)d_ws;
    auto alloc = [&](size_t n) { char* r = p; p += (n + 255) & ~(size_t)255; return r; };
    _Float16* X0  = (_Float16*)alloc((size_t)B_ * IN0 * 2);
    _Float16* X1  = (_Float16*)alloc((size_t)B_ * INTER * 2);
    _Float16* X2  = (_Float16*)alloc((size_t)B_ * INTER * 2);
    _Float16* G1  = (_Float16*)alloc((size_t)B_ * GH * 2);
    float* G2f = (float*)alloc((size_t)B_ * GH * 4);      // reused as P2 after gate_out
    float* cf  = (float*)alloc((size_t)B_ * NE * 4);
    _Float16* T0  = (_Float16*)alloc((size_t)NE * IN0 * HID * 2);
    _Float16* T1  = (_Float16*)alloc((size_t)NE * INTER * HID * 2);
    _Float16* T2  = (_Float16*)alloc((size_t)NE * INTER * ACTD * 2);
    _Float16* G0T = (_Float16*)alloc((size_t)IN0 * GH * 2);
    _Float16* G1T = (_Float16*)alloc((size_t)GH * GH * 2);
    float* P2 = G2f;

    k_prep_g<<<dim3(484), dim3(256), 0, stream>>>(w0, w1, w2, g0w, g1w,
        T0, T1, T2, G0T, G1T);
    k_ln_concat2<<<dim3(B_ / 4), dim3(256), 0, stream>>>(z, c, lng, lnb, X0, X1, X2);

    // gate MLP: X0 -> G1 (fp16) -> G2f (fp32+elu) -> coeff
    k_small64<5, 64, 1, 128, 0><<<dim3(256), dim3(256), 0, stream>>>(
        X0, G0T, g0b, nullptr, G1);
    k_small64<4, 64, 2, 128, 0><<<dim3(256), dim3(256), 0, stream>>>(
        G1, G1T, g1b, G2f, nullptr);
    k_gate_out<<<dim3(B_ / 4), dim3(256), 0, stream>>>(G2f, g2w, g2b, cf);

    // expert layers: fp16 expert-parallel waves, double-buffered, 3 blocks/CU
    k_moe_epar<5><<<dim3(1024), dim3(256), 0, stream>>>(X0, T0, b0, cf, X1);
    k_moe_epar<9><<<dim3(1024), dim3(256), 0, stream>>>(X1, T1, b1, cf, X2);
    // final layer as plain GEMM over N = E*16 = 128, then coeff-mix
    k_small64<9, 32, 0, 128, 0><<<dim3(512), dim3(256), 0, stream>>>(
        X2, T2, b2, P2, nullptr);
    k_mix<<<dim3(B_ * ACTD / 256), dim3(256), 0, stream>>>(P2, cf, out);
}

// Round 13
// 68.101 us; speedup vs baseline: 5.6292x; 1.0361x over previous
//
#include <hip/hip_runtime.h>
#include <math.h>

#define B_     8192
#define LATENT 32
#define CIN    128
#define HID    256
#define ACTD   16
#define NE     8
#define GH     128
#define IN0    160   // LATENT + CIN
#define INTER  288   // HID + LATENT

typedef __attribute__((ext_vector_type(8))) _Float16 half8;
typedef __attribute__((ext_vector_type(4))) float    f32x4;
typedef __attribute__((ext_vector_type(4))) int      i32x4;

__device__ __forceinline__ float elu1(float x) { return x > 0.0f ? x : expm1f(x); }

__device__ __forceinline__ void gload16(const void* g, const char* lds) {
    __builtin_amdgcn_global_load_lds((const __attribute__((address_space(1))) void*)g,
                                     (__attribute__((address_space(3))) void*)lds, 16, 0, 0);
}
__device__ __forceinline__ half8 as_h8(i32x4 v) {
    union U { i32x4 a; half8 b; } u; u.a = v; return u.b;
}

// ---------- prep (gather form): fp16 convert + transpose, coalesced stores ----------
__global__ __launch_bounds__(256) void k_prep_g(
    const float* __restrict__ w0, const float* __restrict__ w1, const float* __restrict__ w2,
    const float* __restrict__ g0w, const float* __restrict__ g1w,
    _Float16* __restrict__ T0, _Float16* __restrict__ T1, _Float16* __restrict__ T2,
    _Float16* __restrict__ G0, _Float16* __restrict__ G1)
{
    int g = blockIdx.x * 256 + threadIdx.x;
    const float* src; int stride; size_t dst; _Float16* H;
    if (g < 40960) {                       // T0: [8][160][256] -> [8*256][160]
        int e = g / 5120, r = g % 5120, o = r / 20, i0 = (r % 20) * 8;
        src = w0 + ((size_t)e * 160 + i0) * 256 + o; stride = 256;
        dst = ((size_t)e * 256 + o) * 160 + i0; H = T0;
    } else if (g < 114688) {               // T1: [8][288][256] -> [8*256][288]
        int t = g - 40960;
        int e = t / 9216, r = t % 9216, o = r / 36, i0 = (r % 36) * 8;
        src = w1 + ((size_t)e * 288 + i0) * 256 + o; stride = 256;
        dst = ((size_t)e * 256 + o) * 288 + i0; H = T1;
    } else if (g < 119296) {               // T2: [8][288][16] -> [8*16][288]
        int t = g - 114688;
        int e = t / 576, r = t % 576, o = r / 36, i0 = (r % 36) * 8;
        src = w2 + ((size_t)e * 288 + i0) * 16 + o; stride = 16;
        dst = ((size_t)e * 16 + o) * 288 + i0; H = T2;
    } else if (g < 121856) {               // G0: [160][128] -> [128][160]
        int t = g - 119296;
        int o = t / 20, i0 = (t % 20) * 8;
        src = g0w + (size_t)i0 * 128 + o; stride = 128;
        dst = (size_t)o * 160 + i0; H = G0;
    } else if (g < 123904) {               // G1: [128][128] -> [128][128]
        int t = g - 121856;
        int o = t / 16, i0 = (t % 16) * 8;
        src = g1w + (size_t)i0 * 128 + o; stride = 128;
        dst = (size_t)o * 128 + i0; H = G1;
    } else return;
    _Float16 hh[8];
    #pragma unroll
    for (int j = 0; j < 8; ++j) hh[j] = (_Float16)src[(size_t)j * stride];
    *(half8*)&H[dst] = *(const half8*)hh;
}

// ---------- LayerNorm + concat to fp16; seed z into X1/X2 ----------
__global__ __launch_bounds__(256) void k_ln_concat2(
    const float* __restrict__ z, const float* __restrict__ c,
    const float* __restrict__ g, const float* __restrict__ bt,
    _Float16* __restrict__ X0, _Float16* __restrict__ X1, _Float16* __restrict__ X2)
{
    int gid = blockIdx.x * 256 + threadIdx.x;
    int row = gid >> 6;
    int l = threadIdx.x & 63;
    if (row >= B_) return;
    const float* cr = c + (size_t)row * CIN;
    float v0 = cr[l], v1 = cr[l + 64];
    float s = v0 + v1;
    #pragma unroll
    for (int o = 32; o; o >>= 1) s += __shfl_xor(s, o);
    float mean = s * (1.0f / 128.0f);
    float d0 = v0 - mean, d1 = v1 - mean;
    float q = d0 * d0 + d1 * d1;
    #pragma unroll
    for (int o = 32; o; o >>= 1) q += __shfl_xor(q, o);
    float rstd = rsqrtf(q * (1.0f / 128.0f) + 1e-5f);
    float y0 = d0 * rstd * g[l] + bt[l];
    float y1 = d1 * rstd * g[l + 64] + bt[l + 64];
    size_t r0 = (size_t)row * IN0;
    X0[r0 + 32 + l] = (_Float16)y0;
    X0[r0 + 96 + l] = (_Float16)y1;
    if (l < LATENT) {
        _Float16 zv = (_Float16)z[(size_t)row * LATENT + l];
        X0[r0 + l] = zv;
        size_t r1 = (size_t)row * INTER;
        X1[r1 + l] = zv;
        X2[r1 + l] = zv;
    }
}

// ---------- fused gate MLP: gate0 -> ELU -> gate1 -> ELU -> gate2 -> softmax ----------
// 128 thr / 2 waves; 32 rows per block; grid 256. H1 stays block-local in a
// XOR-swizzled fp16 LDS tile (write = C-frag layout, read = A-frag layout,
// same involution). H2 stays fp32 in registers; gate2 = in-reg FMA + 16-lane
// shfl reduce; softmax in-wave.
__global__ __launch_bounds__(128, 2) void k_gate_fused(
    const _Float16* __restrict__ X0, const _Float16* __restrict__ G0T,
    const _Float16* __restrict__ G1T,
    const float* __restrict__ g0b, const float* __restrict__ g1b,
    const float* __restrict__ g2w, const float* __restrict__ g2b,
    float* __restrict__ coeff)
{
    __shared__ __align__(16) char smem[53248];   // stage 40KB | h1 8KB | wt_t 4KB
    const int tid = threadIdx.x, wid = tid >> 6, l = tid & 63;
    const int brow = blockIdx.x * 32;
    const int rl16 = wid * 16;

    float* wt_t = (float*)(smem + 49152);        // [8][128] f32

    const int swz = (((l & 3) ^ ((l >> 3) & 3)) << 3);
    const int rq  = l >> 2;
    const int rdo = ((l & 15) << 6) + (((l >> 4) ^ ((l >> 1) & 3)) << 4);

    // ---- stage G0T (40 x 1KB units; waves split) + A0 frags ----
    #pragma unroll
    for (int p = 0; p < 40; ++p) {
        if ((p & 1) != wid) continue;
        const int ks = p / 8, gg = p % 8;
        gload16(G0T + (size_t)(gg * 16 + rq) * IN0 + ks * 32 + swz, smem + p * 1024);
    }
    const _Float16* Ar0 = X0 + (size_t)(brow + rl16 + (l & 15)) * IN0 + (l >> 4) * 8;
    i32x4 a0[5];
    #pragma unroll
    for (int ks = 0; ks < 5; ++ks) a0[ks] = *(const i32x4*)(Ar0 + ks * 32);
    __syncthreads();   // drains stage + a0

    // ---- gate0 GEMM (wave: 16 rows x 128 cols) ----
    f32x4 acc[8];
    #pragma unroll
    for (int nf = 0; nf < 8; ++nf) {
        float bv = g0b[nf * 16 + (l & 15)];
        acc[nf] = (f32x4){bv, bv, bv, bv};
    }
    #pragma unroll
    for (int ks = 0; ks < 5; ++ks)
        #pragma unroll
        for (int nf = 0; nf < 8; ++nf) {
            half8 b = *(const half8*)(smem + (size_t)(ks * 8 + nf) * 1024 + rdo);
            acc[nf] = __builtin_amdgcn_mfma_f32_16x16x32_f16(as_h8(a0[ks]), b, acc[nf], 0, 0, 0);
        }

    // ---- ELU -> h1 LDS (fp16, XOR-swizzled) ----
    char* h1 = smem + 40960;                     // [32 rows][256 B]
    #pragma unroll
    for (int nf = 0; nf < 8; ++nf)
        #pragma unroll
        for (int r = 0; r < 4; ++r) {
            const int rloc = ((l >> 4) << 2) + r;           // 0..15 (== row&15, row&7 = rloc&7)
            const int row = rl16 + rloc;                    // 0..31
            const int colb = (nf * 16 + (l & 15)) * 2;
            *(_Float16*)(h1 + row * 256 + (colb ^ ((rloc & 7) << 4))) = (_Float16)elu1(acc[nf][r]);
        }
    __syncthreads();   // h1 visible; all G0T reads retired

    // ---- stage G1T (32 units) + wt_t; read A1 frags from h1 ----
    #pragma unroll
    for (int p = 0; p < 32; ++p) {
        if ((p & 1) != wid) continue;
        const int ks = p / 8, gg = p % 8;
        gload16(G1T + (size_t)(gg * 16 + rq) * GH + ks * 32 + swz, smem + p * 1024);
    }
    for (int idx = tid; idx < 1024; idx += 128)
        wt_t[(idx & 7) * 128 + (idx >> 3)] = g2w[(idx >> 3) * 8 + (idx & 7)];
    i32x4 a1[4];
    #pragma unroll
    for (int ks = 0; ks < 4; ++ks) {
        const int row = rl16 + (l & 15);
        const int off = (ks * 64 + ((l >> 4) << 4)) ^ ((row & 7) << 4);
        a1[ks] = *(const i32x4*)(h1 + row * 256 + off);
    }
    __syncthreads();   // G1T staged (vmcnt drain) + wt_t visible

    // ---- gate1 GEMM ----
    #pragma unroll
    for (int nf = 0; nf < 8; ++nf) {
        float bv = g1b[nf * 16 + (l & 15)];
        acc[nf] = (f32x4){bv, bv, bv, bv};
    }
    #pragma unroll
    for (int ks = 0; ks < 4; ++ks)
        #pragma unroll
        for (int nf = 0; nf < 8; ++nf) {
            half8 b = *(const half8*)(smem + (size_t)(ks * 8 + nf) * 1024 + rdo);
            acc[nf] = __builtin_amdgcn_mfma_f32_16x16x32_f16(as_h8(a1[ks]), b, acc[nf], 0, 0, 0);
        }

    // ---- gate2 matvec (in-reg) + 16-lane reduce + softmax ----
    float pe[8][4];
    #pragma unroll
    for (int e = 0; e < 8; ++e)
        #pragma unroll
        for (int r = 0; r < 4; ++r) pe[e][r] = 0.f;
    #pragma unroll
    for (int nf = 0; nf < 8; ++nf) {
        float w_[8];
        #pragma unroll
        for (int e = 0; e < 8; ++e) w_[e] = wt_t[e * 128 + nf * 16 + (l & 15)];
        #pragma unroll
        for (int r = 0; r < 4; ++r) {
            float hv = elu1(acc[nf][r]);
            #pragma unroll
            for (int e = 0; e < 8; ++e) pe[e][r] = fmaf(hv, w_[e], pe[e][r]);
        }
    }
    #pragma unroll
    for (int off = 1; off < 16; off <<= 1)
        #pragma unroll
        for (int e = 0; e < 8; ++e)
            #pragma unroll
            for (int r = 0; r < 4; ++r) pe[e][r] += __shfl_xor(pe[e][r], off);

    if ((l & 15) == 0) {
        #pragma unroll
        for (int r = 0; r < 4; ++r) {
            float pv[8];
            float mx = -1e30f;
            #pragma unroll
            for (int e = 0; e < 8; ++e) { pv[e] = pe[e][r] + g2b[e]; mx = fmaxf(mx, pv[e]); }
            float s = 0.f;
            #pragma unroll
            for (int e = 0; e < 8; ++e) { pv[e] = expf(pv[e] - mx); s += pv[e]; }
            float inv = 1.0f / s;
            const int row = brow + rl16 + ((l >> 4) << 2) + r;
            #pragma unroll
            for (int e = 0; e < 8; ++e) coeff[(size_t)row * 8 + e] = pv[e] * inv;
        }
    }
}

// ---------- MoE layer: fp16, expert-parallel waves, double-buffered, 3 blocks/CU ----------
template<int KS>
__global__ __launch_bounds__(256, 3) void k_moe_epar(
    const _Float16* __restrict__ A, const _Float16* __restrict__ Bw,
    const float* __restrict__ bias,   // [8][256]
    const float* __restrict__ coeff,  // [B][8]
    _Float16* __restrict__ outX)
{
    constexpr int K = KS * 32;
    __shared__ __align__(16) char smem[43008];   // 2 bufs x 20480 + cf 2048

    const int tid = threadIdx.x, wid = tid >> 6, l = tid & 63;
    const int brow = (blockIdx.x >> 3) * 64;
    const int bn   = (blockIdx.x & 7) * 32;      // each XCD -> one col slice

    float* cfl = (float*)(smem + 40960);         // [64][8]
    if (tid < 128) {
        f32x4 v = *(const f32x4*)&coeff[(size_t)(brow + (tid >> 1)) * 8 + (tid & 1) * 4];
        *(f32x4*)&cfl[tid * 4] = v;
    }

    const int swz = (((l & 3) ^ ((l >> 3) & 3)) << 3);
    const int rq  = l >> 2;
    const _Float16* sA = A + (size_t)(brow + wid * 16 + rq) * K + swz;
    const _Float16* sB2[2][2];
    #pragma unroll
    for (int e2 = 0; e2 < 2; ++e2)
        #pragma unroll
        for (int gg = 0; gg < 2; ++gg)
            sB2[e2][gg] = Bw + (size_t)((2 * wid + e2) * HID + bn + gg * 16 + rq) * K + swz;

    auto stage = [&](int bi, int k0) {   // 5 gload16 per lane
        char* buf = smem + bi * 20480;
        gload16(sA + k0, buf + wid * 1024);
        #pragma unroll
        for (int e2 = 0; e2 < 2; ++e2)
            #pragma unroll
            for (int gg = 0; gg < 2; ++gg)
                gload16(sB2[e2][gg] + k0,
                        buf + 4096 + (2 * wid + e2) * 2048 + gg * 1024);
    };

    const int rdo = ((l & 15) << 6) + (((l >> 4) ^ ((l >> 1) & 3)) << 4);
    f32x4 acc[2][4][2];
    #pragma unroll
    for (int e2 = 0; e2 < 2; ++e2)
        #pragma unroll
        for (int mf = 0; mf < 4; ++mf)
            #pragma unroll
            for (int nf = 0; nf < 2; ++nf) acc[e2][mf][nf] = (f32x4){0.f, 0.f, 0.f, 0.f};

    stage(0, 0);
    if (KS > 1) stage(1, 32);
    __syncthreads();   // full drain: both bufs + cf

    for (int t = 0; t < KS; ++t) {
        const char* buf = smem + (t & 1) * 20480;
        half8 af[4];
        #pragma unroll
        for (int mf = 0; mf < 4; ++mf)
            af[mf] = *(const half8*)(buf + mf * 1024 + rdo);
        __builtin_amdgcn_s_setprio(1);
        #pragma unroll
        for (int e2 = 0; e2 < 2; ++e2) {
            const char* be = buf + 4096 + (2 * wid + e2) * 2048;
            half8 b0 = *(const half8*)(be + rdo);
            half8 b1 = *(const half8*)(be + 1024 + rdo);
            #pragma unroll
            for (int mf = 0; mf < 4; ++mf) {
                acc[e2][mf][0] = __builtin_amdgcn_mfma_f32_16x16x32_f16(af[mf], b0, acc[e2][mf][0], 0, 0, 0);
                acc[e2][mf][1] = __builtin_amdgcn_mfma_f32_16x16x32_f16(af[mf], b1, acc[e2][mf][1], 0, 0, 0);
            }
        }
        __builtin_amdgcn_s_setprio(0);
        asm volatile("s_waitcnt lgkmcnt(0)" ::: "memory");
        __builtin_amdgcn_sched_barrier(0);
        __builtin_amdgcn_s_barrier();                 // reads of buf(t) retired
        if (t + 2 < KS) stage(t & 1, (t + 2) * 32);   // refill the freed buf
        if (t + 1 < KS) {
            if (t + 2 < KS) { asm volatile("s_waitcnt vmcnt(5)" ::: "memory"); }
            else            { asm volatile("s_waitcnt vmcnt(0)" ::: "memory"); }
            __builtin_amdgcn_s_barrier();             // buf(t+1) ready
            __builtin_amdgcn_sched_barrier(0);
        }
    }

    // ---- epilogue: (acc+bias)*cf per wave-expert pair, cross-wave reduce ----
    const int e0 = 2 * wid, e1 = 2 * wid + 1;
    float bv0[2], bv1[2];
    #pragma unroll
    for (int nf = 0; nf < 2; ++nf) {
        bv0[nf] = bias[e0 * HID + bn + nf * 16 + (l & 15)];
        bv1[nf] = bias[e1 * HID + bn + nf * 16 + (l & 15)];
    }
    float* red = (float*)smem;                        // [4][64][36]
    #pragma unroll
    for (int mf = 0; mf < 4; ++mf) {
        const int rb = mf * 16 + ((l >> 4) << 2);
        #pragma unroll
        for (int r = 0; r < 4; ++r) {
            float c0 = cfl[(rb + r) * 8 + e0];
            float c1 = cfl[(rb + r) * 8 + e1];
            #pragma unroll
            for (int nf = 0; nf < 2; ++nf) {
                float s = (acc[0][mf][nf][r] + bv0[nf]) * c0
                        + (acc[1][mf][nf][r] + bv1[nf]) * c1;
                red[wid * 2304 + (rb + r) * 36 + nf * 16 + (l & 15)] = s;
            }
        }
    }
    __syncthreads();

    const int row = tid >> 2, c0_ = (tid & 3) * 8;
    f32x4 s0 = {0.f, 0.f, 0.f, 0.f}, s1 = {0.f, 0.f, 0.f, 0.f};
    #pragma unroll
    for (int w = 0; w < 4; ++w) {
        s0 += *(const f32x4*)&red[w * 2304 + row * 36 + c0_];
        s1 += *(const f32x4*)&red[w * 2304 + row * 36 + c0_ + 4];
    }
    _Float16 hh[8];
    #pragma unroll
    for (int j = 0; j < 4; ++j) {
        hh[j]     = (_Float16)elu1(s0[j]);
        hh[4 + j] = (_Float16)elu1(s1[j]);
    }
    size_t o = (size_t)(brow + row) * INTER + 32 + bn + c0_;
    *(half8*)&outX[o] = *(const half8*)hh;
}

// ---------- fused final layer + coeff mix: out[b,o] = sum_e cf*(per_e + b2_e) ----------
// 128 thr / 2 waves; 32 rows per block; grid 256. NCOL = 128 (all 8 experts).
__global__ __launch_bounds__(128, 2) void k_final(
    const _Float16* __restrict__ X2, const _Float16* __restrict__ T2,
    const float* __restrict__ b2, const float* __restrict__ cf,
    float* __restrict__ out)
{
    __shared__ __align__(16) char smem[73728];   // 9 ks x 8 g x 1KB
    const int tid = threadIdx.x, wid = tid >> 6, l = tid & 63;
    const int brow = blockIdx.x * 32;

    const int swz = (((l & 3) ^ ((l >> 3) & 3)) << 3);
    const int rq  = l >> 2;
    #pragma unroll
    for (int p = 0; p < 72; ++p) {
        if ((p & 1) != wid) continue;
        const int ks = p / 8, gg = p % 8;
        gload16(T2 + (size_t)(gg * 16 + rq) * INTER + ks * 32 + swz, smem + p * 1024);
    }
    const _Float16* Ar = X2 + (size_t)(brow + wid * 16 + (l & 15)) * INTER + (l >> 4) * 8;
    i32x4 a_[9];
    #pragma unroll
    for (int ks = 0; ks < 9; ++ks) a_[ks] = *(const i32x4*)(Ar + ks * 32);
    __syncthreads();

    const int rdo = ((l & 15) << 6) + (((l >> 4) ^ ((l >> 1) & 3)) << 4);
    f32x4 acc[8];
    #pragma unroll
    for (int nf = 0; nf < 8; ++nf) {
        float bv = b2[nf * 16 + (l & 15)];
        acc[nf] = (f32x4){bv, bv, bv, bv};
    }
    #pragma unroll
    for (int ks = 0; ks < 9; ++ks)
        #pragma unroll
        for (int nf = 0; nf < 8; ++nf) {
            half8 b = *(const half8*)(smem + (size_t)(ks * 8 + nf) * 1024 + rdo);
            acc[nf] = __builtin_amdgcn_mfma_f32_16x16x32_f16(as_h8(a_[ks]), b, acc[nf], 0, 0, 0);
        }

    #pragma unroll
    for (int r = 0; r < 4; ++r) {
        const int row = brow + wid * 16 + ((l >> 4) << 2) + r;
        const float* cr = cf + (size_t)row * 8;
        float s = 0.f;
        #pragma unroll
        for (int e = 0; e < 8; ++e) s = fmaf(cr[e], acc[e][r], s);
        out[(size_t)row * ACTD + (l & 15)] = s;
    }
}

extern "C" void kernel_launch(void* const* d_in, const int* in_sizes, int n_in,
                              void* d_out, int out_size, void* d_ws, size_t ws_size,
                              hipStream_t stream)
{
    (void)in_sizes; (void)n_in; (void)out_size; (void)ws_size;
    const float* z   = (const float*)d_in[0];
    const float* c   = (const float*)d_in[1];
    const float* w0  = (const float*)d_in[2];
    const float* b0  = (const float*)d_in[3];
    const float* w1  = (const float*)d_in[4];
    const float* b1  = (const float*)d_in[5];
    const float* w2  = (const float*)d_in[6];
    const float* b2  = (const float*)d_in[7];
    const float* g0w = (const float*)d_in[8];
    const float* g0b = (const float*)d_in[9];
    const float* g1w = (const float*)d_in[10];
    const float* g1b = (const float*)d_in[11];
    const float* g2w = (const float*)d_in[12];
    const float* g2b = (const float*)d_in[13];
    const float* lng = (const float*)d_in[14];
    const float* lnb = (const float*)d_in[15];
    float* out = (float*)d_out;

    char* p = (char*)d_ws;
    auto alloc = [&](size_t n) { char* r = p; p += (n + 255) & ~(size_t)255; return r; };
    _Float16* X0  = (_Float16*)alloc((size_t)B_ * IN0 * 2);
    _Float16* X1  = (_Float16*)alloc((size_t)B_ * INTER * 2);
    _Float16* X2  = (_Float16*)alloc((size_t)B_ * INTER * 2);
    float* cf  = (float*)alloc((size_t)B_ * NE * 4);
    _Float16* T0  = (_Float16*)alloc((size_t)NE * IN0 * HID * 2);
    _Float16* T1  = (_Float16*)alloc((size_t)NE * INTER * HID * 2);
    _Float16* T2  = (_Float16*)alloc((size_t)NE * INTER * ACTD * 2);
    _Float16* G0T = (_Float16*)alloc((size_t)IN0 * GH * 2);
    _Float16* G1T = (_Float16*)alloc((size_t)GH * GH * 2);

    k_prep_g<<<dim3(484), dim3(256), 0, stream>>>(w0, w1, w2, g0w, g1w,
        T0, T1, T2, G0T, G1T);
    k_ln_concat2<<<dim3(B_ / 4), dim3(256), 0, stream>>>(z, c, lng, lnb, X0, X1, X2);

    // fused gate MLP -> coeff
    k_gate_fused<<<dim3(256), dim3(128), 0, stream>>>(
        X0, G0T, G1T, g0b, g1b, g2w, g2b, cf);

    // expert layers: fp16 expert-parallel waves, double-buffered, 3 blocks/CU
    k_moe_epar<5><<<dim3(1024), dim3(256), 0, stream>>>(X0, T0, b0, cf, X1);
    k_moe_epar<9><<<dim3(1024), dim3(256), 0, stream>>>(X1, T1, b1, cf, X2);

    // fused final layer + mix
    k_final<<<dim3(256), dim3(128), 0, stream>>>(X2, T2, b2, cf, out);
}

// Round 14
// 64.629 us; speedup vs baseline: 5.9315x; 1.0537x over previous
//
#include <hip/hip_runtime.h>
#include <math.h>

#define B_     8192
#define LATENT 32
#define CIN    128
#define HID    256
#define ACTD   16
#define NE     8
#define GH     128
#define IN0    160   // LATENT + CIN
#define INTER  288   // HID + LATENT

typedef __attribute__((ext_vector_type(8))) _Float16 half8;
typedef __attribute__((ext_vector_type(4))) float    f32x4;
typedef __attribute__((ext_vector_type(4))) int      i32x4;

__device__ __forceinline__ float elu1(float x) { return x > 0.0f ? x : expm1f(x); }

__device__ __forceinline__ void gload16(const void* g, const char* lds) {
    __builtin_amdgcn_global_load_lds((const __attribute__((address_space(1))) void*)g,
                                     (__attribute__((address_space(3))) void*)lds, 16, 0, 0);
}
__device__ __forceinline__ half8 as_h8(i32x4 v) {
    union U { i32x4 a; half8 b; } u; u.a = v; return u.b;
}

// ---------- fused prep (weight transpose+fp16) and LayerNorm/concat ----------
__global__ __launch_bounds__(256) void k_prep_ln(
    const float* __restrict__ w0, const float* __restrict__ w1, const float* __restrict__ w2,
    const float* __restrict__ g0w, const float* __restrict__ g1w,
    const float* __restrict__ z, const float* __restrict__ c,
    const float* __restrict__ g, const float* __restrict__ bt,
    _Float16* __restrict__ T0, _Float16* __restrict__ T1, _Float16* __restrict__ T2,
    _Float16* __restrict__ G0, _Float16* __restrict__ G1,
    _Float16* __restrict__ X0, _Float16* __restrict__ X1, _Float16* __restrict__ X2)
{
    if (blockIdx.x < 484) {
        int gq = blockIdx.x * 256 + threadIdx.x;
        const float* src; int stride; size_t dst; _Float16* H;
        if (gq < 40960) {                      // T0: [8][160][256] -> [8*256][160]
            int e = gq / 5120, r = gq % 5120, o = r / 20, i0 = (r % 20) * 8;
            src = w0 + ((size_t)e * 160 + i0) * 256 + o; stride = 256;
            dst = ((size_t)e * 256 + o) * 160 + i0; H = T0;
        } else if (gq < 114688) {              // T1
            int t = gq - 40960;
            int e = t / 9216, r = t % 9216, o = r / 36, i0 = (r % 36) * 8;
            src = w1 + ((size_t)e * 288 + i0) * 256 + o; stride = 256;
            dst = ((size_t)e * 256 + o) * 288 + i0; H = T1;
        } else if (gq < 119296) {              // T2
            int t = gq - 114688;
            int e = t / 576, r = t % 576, o = r / 36, i0 = (r % 36) * 8;
            src = w2 + ((size_t)e * 288 + i0) * 16 + o; stride = 16;
            dst = ((size_t)e * 16 + o) * 288 + i0; H = T2;
        } else if (gq < 121856) {              // G0
            int t = gq - 119296;
            int o = t / 20, i0 = (t % 20) * 8;
            src = g0w + (size_t)i0 * 128 + o; stride = 128;
            dst = (size_t)o * 160 + i0; H = G0;
        } else if (gq < 123904) {              // G1
            int t = gq - 121856;
            int o = t / 16, i0 = (t % 16) * 8;
            src = g1w + (size_t)i0 * 128 + o; stride = 128;
            dst = (size_t)o * 128 + i0; H = G1;
        } else return;
        _Float16 hh[8];
        #pragma unroll
        for (int j = 0; j < 8; ++j) hh[j] = (_Float16)src[(size_t)j * stride];
        *(half8*)&H[dst] = *(const half8*)hh;
        return;
    }
    // ---- LayerNorm branch ----
    int gid = (blockIdx.x - 484) * 256 + threadIdx.x;
    int row = gid >> 6;
    int l = threadIdx.x & 63;
    const float* cr = c + (size_t)row * CIN;
    float v0 = cr[l], v1 = cr[l + 64];
    float s = v0 + v1;
    #pragma unroll
    for (int o = 32; o; o >>= 1) s += __shfl_xor(s, o);
    float mean = s * (1.0f / 128.0f);
    float d0 = v0 - mean, d1 = v1 - mean;
    float q = d0 * d0 + d1 * d1;
    #pragma unroll
    for (int o = 32; o; o >>= 1) q += __shfl_xor(q, o);
    float rstd = rsqrtf(q * (1.0f / 128.0f) + 1e-5f);
    float y0 = d0 * rstd * g[l] + bt[l];
    float y1 = d1 * rstd * g[l + 64] + bt[l + 64];
    size_t r0 = (size_t)row * IN0;
    X0[r0 + 32 + l] = (_Float16)y0;
    X0[r0 + 96 + l] = (_Float16)y1;
    if (l < LATENT) {
        _Float16 zv = (_Float16)z[(size_t)row * LATENT + l];
        X0[r0 + l] = zv;
        size_t r1 = (size_t)row * INTER;
        X1[r1 + l] = zv;
        X2[r1 + l] = zv;
    }
}

// ---------- fused gate MLP: both weight stages issued up-front (no mid stall) ----------
__global__ __launch_bounds__(128, 2) void k_gate_fused(
    const _Float16* __restrict__ X0, const _Float16* __restrict__ G0T,
    const _Float16* __restrict__ G1T,
    const float* __restrict__ g0b, const float* __restrict__ g1b,
    const float* __restrict__ g2w, const float* __restrict__ g2b,
    float* __restrict__ coeff)
{
    __shared__ __align__(16) char smem[86016];   // G0 40KB | G1 32KB | h1 8KB | wt_t 4KB
    const int tid = threadIdx.x, wid = tid >> 6, l = tid & 63;
    const int brow = blockIdx.x * 32;
    const int rl16 = wid * 16;

    char* sG1  = smem + 40960;
    char* h1   = smem + 73728;                   // [32 rows][256 B]
    float* wt_t = (float*)(smem + 81920);        // [8][128] f32

    const int swz = (((l & 3) ^ ((l >> 3) & 3)) << 3);
    const int rq  = l >> 2;
    const int rdo = ((l & 15) << 6) + (((l >> 4) ^ ((l >> 1) & 3)) << 4);

    // ---- issue ALL stages: G0 (20/lane), G1 (16/lane), A0 frags, wt_t ----
    #pragma unroll
    for (int p = 0; p < 40; ++p) {
        if ((p & 1) != wid) continue;
        const int ks = p / 8, gg = p % 8;
        gload16(G0T + (size_t)(gg * 16 + rq) * IN0 + ks * 32 + swz, smem + p * 1024);
    }
    #pragma unroll
    for (int p = 0; p < 32; ++p) {
        if ((p & 1) != wid) continue;
        const int ks = p / 8, gg = p % 8;
        gload16(G1T + (size_t)(gg * 16 + rq) * GH + ks * 32 + swz, sG1 + p * 1024);
    }
    const _Float16* Ar0 = X0 + (size_t)(brow + rl16 + (l & 15)) * IN0 + (l >> 4) * 8;
    i32x4 a0[5];
    #pragma unroll
    for (int ks = 0; ks < 5; ++ks) a0[ks] = *(const i32x4*)(Ar0 + ks * 32);
    for (int idx = tid; idx < 1024; idx += 128)
        wt_t[(idx & 7) * 128 + (idx >> 3)] = g2w[(idx >> 3) * 8 + (idx & 7)];
    __syncthreads();   // full drain: everything staged

    // ---- gate0 GEMM (wave: 16 rows x 128 cols) ----
    f32x4 acc[8];
    #pragma unroll
    for (int nf = 0; nf < 8; ++nf) {
        float bv = g0b[nf * 16 + (l & 15)];
        acc[nf] = (f32x4){bv, bv, bv, bv};
    }
    #pragma unroll
    for (int ks = 0; ks < 5; ++ks)
        #pragma unroll
        for (int nf = 0; nf < 8; ++nf) {
            half8 b = *(const half8*)(smem + (size_t)(ks * 8 + nf) * 1024 + rdo);
            acc[nf] = __builtin_amdgcn_mfma_f32_16x16x32_f16(as_h8(a0[ks]), b, acc[nf], 0, 0, 0);
        }

    // ---- ELU -> h1 LDS (fp16, XOR-swizzled) ----
    #pragma unroll
    for (int nf = 0; nf < 8; ++nf)
        #pragma unroll
        for (int r = 0; r < 4; ++r) {
            const int rloc = ((l >> 4) << 2) + r;
            const int row = rl16 + rloc;
            const int colb = (nf * 16 + (l & 15)) * 2;
            *(_Float16*)(h1 + row * 256 + (colb ^ ((rloc & 7) << 4))) = (_Float16)elu1(acc[nf][r]);
        }
    __syncthreads();   // h1 visible

    i32x4 a1[4];
    #pragma unroll
    for (int ks = 0; ks < 4; ++ks) {
        const int row = rl16 + (l & 15);
        const int off = (ks * 64 + ((l >> 4) << 4)) ^ ((row & 7) << 4);
        a1[ks] = *(const i32x4*)(h1 + row * 256 + off);
    }

    // ---- gate1 GEMM (weights already resident) ----
    #pragma unroll
    for (int nf = 0; nf < 8; ++nf) {
        float bv = g1b[nf * 16 + (l & 15)];
        acc[nf] = (f32x4){bv, bv, bv, bv};
    }
    #pragma unroll
    for (int ks = 0; ks < 4; ++ks)
        #pragma unroll
        for (int nf = 0; nf < 8; ++nf) {
            half8 b = *(const half8*)(sG1 + (size_t)(ks * 8 + nf) * 1024 + rdo);
            acc[nf] = __builtin_amdgcn_mfma_f32_16x16x32_f16(as_h8(a1[ks]), b, acc[nf], 0, 0, 0);
        }

    // ---- gate2 matvec + 16-lane reduce + softmax ----
    float pe[8][4];
    #pragma unroll
    for (int e = 0; e < 8; ++e)
        #pragma unroll
        for (int r = 0; r < 4; ++r) pe[e][r] = 0.f;
    #pragma unroll
    for (int nf = 0; nf < 8; ++nf) {
        float w_[8];
        #pragma unroll
        for (int e = 0; e < 8; ++e) w_[e] = wt_t[e * 128 + nf * 16 + (l & 15)];
        #pragma unroll
        for (int r = 0; r < 4; ++r) {
            float hv = elu1(acc[nf][r]);
            #pragma unroll
            for (int e = 0; e < 8; ++e) pe[e][r] = fmaf(hv, w_[e], pe[e][r]);
        }
    }
    #pragma unroll
    for (int off = 1; off < 16; off <<= 1)
        #pragma unroll
        for (int e = 0; e < 8; ++e)
            #pragma unroll
            for (int r = 0; r < 4; ++r) pe[e][r] += __shfl_xor(pe[e][r], off);

    if ((l & 15) == 0) {
        #pragma unroll
        for (int r = 0; r < 4; ++r) {
            float pv[8];
            float mx = -1e30f;
            #pragma unroll
            for (int e = 0; e < 8; ++e) { pv[e] = pe[e][r] + g2b[e]; mx = fmaxf(mx, pv[e]); }
            float s = 0.f;
            #pragma unroll
            for (int e = 0; e < 8; ++e) { pv[e] = expf(pv[e] - mx); s += pv[e]; }
            float inv = 1.0f / s;
            const int row = brow + rl16 + ((l >> 4) << 2) + r;
            #pragma unroll
            for (int e = 0; e < 8; ++e) coeff[(size_t)row * 8 + e] = pv[e] * inv;
        }
    }
}

// ---------- MoE layer: fp16 epar, robust XCD-agnostic bn (high bits) ----------
template<int KS>
__global__ __launch_bounds__(256, 3) void k_moe_epar(
    const _Float16* __restrict__ A, const _Float16* __restrict__ Bw,
    const float* __restrict__ bias,   // [8][256]
    const float* __restrict__ coeff,  // [B][8]
    _Float16* __restrict__ outX)
{
    constexpr int K = KS * 32;
    __shared__ __align__(16) char smem[43008];   // 2 bufs x 20480 + cf 2048

    const int tid = threadIdx.x, wid = tid >> 6, l = tid & 63;
    // robust mapping: any 128-consecutive-bid window shares one bn slice
    const int brow = (blockIdx.x & 127) * 64;
    const int bn   = (blockIdx.x >> 7) * 32;

    float* cfl = (float*)(smem + 40960);         // [64][8]
    if (tid < 128) {
        f32x4 v = *(const f32x4*)&coeff[(size_t)(brow + (tid >> 1)) * 8 + (tid & 1) * 4];
        *(f32x4*)&cfl[tid * 4] = v;
    }

    const int swz = (((l & 3) ^ ((l >> 3) & 3)) << 3);
    const int rq  = l >> 2;
    const _Float16* sA = A + (size_t)(brow + wid * 16 + rq) * K + swz;
    const _Float16* sB2[2][2];
    #pragma unroll
    for (int e2 = 0; e2 < 2; ++e2)
        #pragma unroll
        for (int gg = 0; gg < 2; ++gg)
            sB2[e2][gg] = Bw + (size_t)((2 * wid + e2) * HID + bn + gg * 16 + rq) * K + swz;

    auto stage = [&](int bi, int k0) {   // 5 gload16 per lane
        char* buf = smem + bi * 20480;
        gload16(sA + k0, buf + wid * 1024);
        #pragma unroll
        for (int e2 = 0; e2 < 2; ++e2)
            #pragma unroll
            for (int gg = 0; gg < 2; ++gg)
                gload16(sB2[e2][gg] + k0,
                        buf + 4096 + (2 * wid + e2) * 2048 + gg * 1024);
    };

    const int rdo = ((l & 15) << 6) + (((l >> 4) ^ ((l >> 1) & 3)) << 4);
    f32x4 acc[2][4][2];
    #pragma unroll
    for (int e2 = 0; e2 < 2; ++e2)
        #pragma unroll
        for (int mf = 0; mf < 4; ++mf)
            #pragma unroll
            for (int nf = 0; nf < 2; ++nf) acc[e2][mf][nf] = (f32x4){0.f, 0.f, 0.f, 0.f};

    stage(0, 0);
    if (KS > 1) stage(1, 32);
    __syncthreads();   // full drain: both bufs + cf

    for (int t = 0; t < KS; ++t) {
        const char* buf = smem + (t & 1) * 20480;
        half8 af[4];
        #pragma unroll
        for (int mf = 0; mf < 4; ++mf)
            af[mf] = *(const half8*)(buf + mf * 1024 + rdo);
        __builtin_amdgcn_s_setprio(1);
        #pragma unroll
        for (int e2 = 0; e2 < 2; ++e2) {
            const char* be = buf + 4096 + (2 * wid + e2) * 2048;
            half8 b0 = *(const half8*)(be + rdo);
            half8 b1 = *(const half8*)(be + 1024 + rdo);
            #pragma unroll
            for (int mf = 0; mf < 4; ++mf) {
                acc[e2][mf][0] = __builtin_amdgcn_mfma_f32_16x16x32_f16(af[mf], b0, acc[e2][mf][0], 0, 0, 0);
                acc[e2][mf][1] = __builtin_amdgcn_mfma_f32_16x16x32_f16(af[mf], b1, acc[e2][mf][1], 0, 0, 0);
            }
        }
        __builtin_amdgcn_s_setprio(0);
        asm volatile("s_waitcnt lgkmcnt(0)" ::: "memory");
        __builtin_amdgcn_sched_barrier(0);
        __builtin_amdgcn_s_barrier();                 // reads of buf(t) retired
        if (t + 2 < KS) stage(t & 1, (t + 2) * 32);   // refill the freed buf
        if (t + 1 < KS) {
            if (t + 2 < KS) { asm volatile("s_waitcnt vmcnt(5)" ::: "memory"); }
            else            { asm volatile("s_waitcnt vmcnt(0)" ::: "memory"); }
            __builtin_amdgcn_s_barrier();             // buf(t+1) ready
            __builtin_amdgcn_sched_barrier(0);
        }
    }

    // ---- epilogue: (acc+bias)*cf per wave-expert pair, cross-wave reduce ----
    const int e0 = 2 * wid, e1 = 2 * wid + 1;
    float bv0[2], bv1[2];
    #pragma unroll
    for (int nf = 0; nf < 2; ++nf) {
        bv0[nf] = bias[e0 * HID + bn + nf * 16 + (l & 15)];
        bv1[nf] = bias[e1 * HID + bn + nf * 16 + (l & 15)];
    }
    float* red = (float*)smem;                        // [4][64][36]
    #pragma unroll
    for (int mf = 0; mf < 4; ++mf) {
        const int rb = mf * 16 + ((l >> 4) << 2);
        #pragma unroll
        for (int r = 0; r < 4; ++r) {
            float c0 = cfl[(rb + r) * 8 + e0];
            float c1 = cfl[(rb + r) * 8 + e1];
            #pragma unroll
            for (int nf = 0; nf < 2; ++nf) {
                float s = (acc[0][mf][nf][r] + bv0[nf]) * c0
                        + (acc[1][mf][nf][r] + bv1[nf]) * c1;
                red[wid * 2304 + (rb + r) * 36 + nf * 16 + (l & 15)] = s;
            }
        }
    }
    __syncthreads();

    const int row = tid >> 2, c0_ = (tid & 3) * 8;
    f32x4 s0 = {0.f, 0.f, 0.f, 0.f}, s1 = {0.f, 0.f, 0.f, 0.f};
    #pragma unroll
    for (int w = 0; w < 4; ++w) {
        s0 += *(const f32x4*)&red[w * 2304 + row * 36 + c0_];
        s1 += *(const f32x4*)&red[w * 2304 + row * 36 + c0_ + 4];
    }
    _Float16 hh[8];
    #pragma unroll
    for (int j = 0; j < 4; ++j) {
        hh[j]     = (_Float16)elu1(s0[j]);
        hh[4 + j] = (_Float16)elu1(s1[j]);
    }
    size_t o = (size_t)(brow + row) * INTER + 32 + bn + c0_;
    *(half8*)&outX[o] = *(const half8*)hh;
}

// ---------- fused final layer + mix: ks-pipelined staging via counted vmcnt ----------
__global__ __launch_bounds__(128, 2) void k_final(
    const _Float16* __restrict__ X2, const _Float16* __restrict__ T2,
    const float* __restrict__ b2, const float* __restrict__ cf,
    float* __restrict__ out)
{
    __shared__ __align__(16) char smem[73728];   // 9 ks x 8 g x 1KB
    const int tid = threadIdx.x, wid = tid >> 6, l = tid & 63;
    const int brow = blockIdx.x * 32;

    // A-frags first (oldest in vmcnt FIFO)
    const _Float16* Ar = X2 + (size_t)(brow + wid * 16 + (l & 15)) * INTER + (l >> 4) * 8;
    i32x4 a_[9];
    #pragma unroll
    for (int ks = 0; ks < 9; ++ks) a_[ks] = *(const i32x4*)(Ar + ks * 32);

    // stage units in ks-ascending order (4 gloads/lane per ks)
    const int swz = (((l & 3) ^ ((l >> 3) & 3)) << 3);
    const int rq  = l >> 2;
    #pragma unroll
    for (int p = 0; p < 72; ++p) {
        if ((p & 1) != wid) continue;
        const int ks = p / 8, gg = p % 8;
        gload16(T2 + (size_t)(gg * 16 + rq) * INTER + ks * 32 + swz, smem + p * 1024);
    }

    const int rdo = ((l & 15) << 6) + (((l >> 4) ^ ((l >> 1) & 3)) << 4);
    f32x4 acc[8];
    #pragma unroll
    for (int nf = 0; nf < 8; ++nf) {
        float bv = b2[nf * 16 + (l & 15)];
        acc[nf] = (f32x4){bv, bv, bv, bv};
    }
    #pragma unroll
    for (int ks = 0; ks < 9; ++ks) {
        // a_ (9) oldest, then 36 stage loads; ks ready when outstanding <= 32-4*ks
        switch (ks) {
            case 0: asm volatile("s_waitcnt vmcnt(32)" ::: "memory"); break;
            case 1: asm volatile("s_waitcnt vmcnt(28)" ::: "memory"); break;
            case 2: asm volatile("s_waitcnt vmcnt(24)" ::: "memory"); break;
            case 3: asm volatile("s_waitcnt vmcnt(20)" ::: "memory"); break;
            case 4: asm volatile("s_waitcnt vmcnt(16)" ::: "memory"); break;
            case 5: asm volatile("s_waitcnt vmcnt(12)" ::: "memory"); break;
            case 6: asm volatile("s_waitcnt vmcnt(8)"  ::: "memory"); break;
            case 7: asm volatile("s_waitcnt vmcnt(4)"  ::: "memory"); break;
            default: asm volatile("s_waitcnt vmcnt(0)" ::: "memory"); break;
        }
        __builtin_amdgcn_s_barrier();
        __builtin_amdgcn_sched_barrier(0);
        if (ks == 0) {
            #pragma unroll
            for (int k2 = 0; k2 < 9; ++k2) asm volatile("" : "+v"(a_[k2]));
        }
        #pragma unroll
        for (int nf = 0; nf < 8; ++nf) {
            half8 b = *(const half8*)(smem + (size_t)(ks * 8 + nf) * 1024 + rdo);
            acc[nf] = __builtin_amdgcn_mfma_f32_16x16x32_f16(as_h8(a_[ks]), b, acc[nf], 0, 0, 0);
        }
    }

    #pragma unroll
    for (int r = 0; r < 4; ++r) {
        const int row = brow + wid * 16 + ((l >> 4) << 2) + r;
        const float* cr = cf + (size_t)row * 8;
        float s = 0.f;
        #pragma unroll
        for (int e = 0; e < 8; ++e) s = fmaf(cr[e], acc[e][r], s);
        out[(size_t)row * ACTD + (l & 15)] = s;
    }
}

extern "C" void kernel_launch(void* const* d_in, const int* in_sizes, int n_in,
                              void* d_out, int out_size, void* d_ws, size_t ws_size,
                              hipStream_t stream)
{
    (void)in_sizes; (void)n_in; (void)out_size; (void)ws_size;
    const float* z   = (const float*)d_in[0];
    const float* c   = (const float*)d_in[1];
    const float* w0  = (const float*)d_in[2];
    const float* b0  = (const float*)d_in[3];
    const float* w1  = (const float*)d_in[4];
    const float* b1  = (const float*)d_in[5];
    const float* w2  = (const float*)d_in[6];
    const float* b2  = (const float*)d_in[7];
    const float* g0w = (const float*)d_in[8];
    const float* g0b = (const float*)d_in[9];
    const float* g1w = (const float*)d_in[10];
    const float* g1b = (const float*)d_in[11];
    const float* g2w = (const float*)d_in[12];
    const float* g2b = (const float*)d_in[13];
    const float* lng = (const float*)d_in[14];
    const float* lnb = (const float*)d_in[15];
    float* out = (float*)d_out;

    char* p = (char*)d_ws;
    auto alloc = [&](size_t n) { char* r = p; p += (n + 255) & ~(size_t)255; return r; };
    _Float16* X0  = (_Float16*)alloc((size_t)B_ * IN0 * 2);
    _Float16* X1  = (_Float16*)alloc((size_t)B_ * INTER * 2);
    _Float16* X2  = (_Float16*)alloc((size_t)B_ * INTER * 2);
    float* cf  = (float*)alloc((size_t)B_ * NE * 4);
    _Float16* T0  = (_Float16*)alloc((size_t)NE * IN0 * HID * 2);
    _Float16* T1  = (_Float16*)alloc((size_t)NE * INTER * HID * 2);
    _Float16* T2  = (_Float16*)alloc((size_t)NE * INTER * ACTD * 2);
    _Float16* G0T = (_Float16*)alloc((size_t)IN0 * GH * 2);
    _Float16* G1T = (_Float16*)alloc((size_t)GH * GH * 2);

    k_prep_ln<<<dim3(484 + B_ / 4), dim3(256), 0, stream>>>(
        w0, w1, w2, g0w, g1w, z, c, lng, lnb,
        T0, T1, T2, G0T, G1T, X0, X1, X2);

    // fused gate MLP -> coeff
    k_gate_fused<<<dim3(256), dim3(128), 0, stream>>>(
        X0, G0T, G1T, g0b, g1b, g2w, g2b, cf);

    // expert layers
    k_moe_epar<5><<<dim3(1024), dim3(256), 0, stream>>>(X0, T0, b0, cf, X1);
    k_moe_epar<9><<<dim3(1024), dim3(256), 0, stream>>>(X1, T1, b1, cf, X2);

    // fused final layer + mix
    k_final<<<dim3(256), dim3(128), 0, stream>>>(X2, T2, b2, cf, out);
}